// Round 8
// baseline (279.834 us; speedup 1.0000x reference)
//
#include <hip/hip_runtime.h>
#include <hip/hip_fp16.h>

#define N_NODES 50000
#define N_EDGES 800000
#define N_GRAPHS 512
#define VOCAB 10000
#define C 128
#define NBUCK 196            // ceil(50000/256), bucket = dst>>8
#define A_BLOCKS 200         // 4000 edges each
#define EDGES_PER_A (N_EDGES / A_BLOCKS)
#define SE_CAP 8192          // LDS eSrc staging per bucket (mean 4096)

typedef __attribute__((ext_vector_type(8))) short short8v;
typedef __attribute__((ext_vector_type(4))) float f32x4;

__device__ __forceinline__ unsigned short f2bf(float f){
  unsigned u = __builtin_bit_cast(unsigned, f);
  unsigned r = u + 0x7FFFu + ((u >> 16) & 1u);
  return (unsigned short)(r >> 16);
}
__device__ __forceinline__ float bf2f(unsigned short h){
  unsigned u = ((unsigned)h) << 16;
  return __builtin_bit_cast(float, u);
}

// ---------- binning A1: per-block bucket histograms ----------
__global__ __launch_bounds__(256) void k_binCount(const int* __restrict__ dst, int* __restrict__ blockHist){
  __shared__ int h[256];
  int t = threadIdx.x;
  h[t] = 0; __syncthreads();
  int base = blockIdx.x * EDGES_PER_A;
  for (int i = t; i < EDGES_PER_A; i += 256)
    atomicAdd(&h[dst[base+i] >> 8], 1);
  __syncthreads();
  blockHist[blockIdx.x*256 + t] = h[t];
}

// ---------- scan: bucketBase + per-block chunk offsets ----------
__global__ void k_binScan(const int* __restrict__ blockHist, int* __restrict__ blockOfs,
                          int* __restrict__ bucketBase){
  __shared__ int s[256];
  int t = threadIdx.x;
  int run = 0;
  for (int b = 0; b < A_BLOCKS; b++){
    int v = blockHist[b*256 + t];
    blockOfs[b*256 + t] = run;
    run += v;
  }
  s[t] = run; __syncthreads();
  for (int off=1; off<256; off<<=1){
    int u = (t>=off) ? s[t-off] : 0;
    __syncthreads();
    s[t] += u;
    __syncthreads();
  }
  bucketBase[t+1] = s[t];
  if (t == 0) bucketBase[0] = 0;
}

// ---------- binning A2: scatter packed edges (no global atomics) ----------
__global__ __launch_bounds__(256) void k_binScatter(const int* __restrict__ src, const int* __restrict__ dst,
                           const int* __restrict__ bucketBase, const int* __restrict__ blockOfs,
                           unsigned* __restrict__ binned){
  __shared__ int ofs[256], cur[256];
  int t = threadIdx.x;
  ofs[t] = bucketBase[t] + blockOfs[blockIdx.x*256 + t];
  cur[t] = 0;
  __syncthreads();
  int base = blockIdx.x * EDGES_PER_A;
  for (int i = t; i < EDGES_PER_A; i += 256){
    int d = dst[base+i];
    int b = d >> 8;
    int p = atomicAdd(&cur[b], 1);
    binned[ofs[b] + p] = (unsigned)(src[base+i] & 0xFFFF) | ((unsigned)(d & 0xFF) << 16);
  }
}

// ---------- binning B: per-bucket CSR finalize ----------
__global__ __launch_bounds__(256) void k_binFinal(const unsigned* __restrict__ binned,
                         const int* __restrict__ bucketBase,
                         unsigned short* __restrict__ eSrc, int* __restrict__ rowStart,
                         int* __restrict__ deg, float* __restrict__ dinv){
  __shared__ int h[256], pre[256], cur[256];
  __shared__ unsigned short sE[SE_CAP];
  int b = blockIdx.x;
  int t = threadIdx.x;
  int base = bucketBase[b], cnt = bucketBase[b+1] - base;
  int nodeBase = b << 8;
  h[t] = 0; __syncthreads();
  for (int i = t; i < cnt; i += 256)
    atomicAdd(&h[binned[base+i] >> 16], 1);
  __syncthreads();
  pre[t] = h[t]; __syncthreads();
  for (int off=1; off<256; off<<=1){
    int u = (t>=off) ? pre[t-off] : 0;
    __syncthreads();
    pre[t] += u;
    __syncthreads();
  }
  int node = nodeBase + t;
  if (node < N_NODES){
    int d = h[t];
    deg[node] = d;
    rowStart[node] = base + pre[t] - d;
    dinv[node] = rsqrtf((float)d + 1.0f);
  }
  cur[t] = pre[t] - h[t];
  __syncthreads();
  for (int i = t; i < cnt; i += 256){
    unsigned v = binned[base+i];
    int dl = v >> 16;
    int p = atomicAdd(&cur[dl], 1);
    unsigned short s = (unsigned short)(v & 0xFFFF);
    if (p < SE_CAP) sE[p] = s;
    else eSrc[base + p] = s;
  }
  __syncthreads();
  int lim = cnt < SE_CAP ? cnt : SE_CAP;
  for (int i = t; i < lim; i += 256) eSrc[base+i] = sE[i];
}

// ---------- prep: gstart | W-prepack | emb->fp16 ----------
__global__ __launch_bounds__(256) void k_prep(const int* __restrict__ batch, int* __restrict__ gStart,
                       const float* __restrict__ W1, const float* __restrict__ W2,
                       const float* __restrict__ W3, short* __restrict__ Bp,
                       const float* __restrict__ emb, __half* __restrict__ embh){
  int b = blockIdx.x, t = threadIdx.x;
  if (b < NBUCK){                       // gstart
    int i = b*256 + t;
    if (i >= N_NODES) return;
    int bb = batch[i];
    int pb = (i==0) ? -1 : batch[i-1];
    for (int g=pb+1; g<=bb; g++) gStart[g] = i;
    if (i == N_NODES-1)
      for (int g=bb+1; g<=N_GRAPHS; g++) gStart[g] = N_NODES;
  } else if (b < NBUCK+24){             // W prepack (3 layers x 2048 threads)
    int idx = (b-NBUCK)*256 + t;        // 0..6143
    int layer = idx / 2048;
    int r = idx - layer*2048;
    const float* W = (layer==0) ? W1 : (layer==1) ? W2 : W3;
    short* Bh = Bp + (size_t)layer*32768;
    short* Bl = Bh + 16384;
    int lane = r & 63, tile = r >> 6;   // tile = kt*8 + ct
    int kt = tile >> 3, ct = tile & 7;
    int q = lane >> 4, c = ct*16 + (lane & 15);
    #pragma unroll
    for (int i=0;i<8;i++){
      int k = kt*32 + q*8 + i;
      float w = W[k*C + c];
      unsigned short hh = f2bf(w);
      unsigned short ll = f2bf(w - bf2f(hh));
      Bh[(size_t)(tile*64 + lane)*8 + i] = (short)hh;
      Bl[(size_t)(tile*64 + lane)*8 + i] = (short)ll;
    }
  } else {                              // emb -> fp16 (64 blocks)
    int idx = (b-NBUCK-24)*256 + t;
    const float2* s = (const float2*)emb;
    __half2* d2 = (__half2*)embh;
    for (int i = idx; i < VOCAB*C/2; i += 64*256)
      d2[i] = __float22half2_rn(s[i]);
  }
}

// ---------- shared MFMA core: LDS u-tile (32x128 f16, XOR-swizzled) x W frags ----------
// wave w owns column-tiles ct = 2w, 2w+1; acc[T][c] covers rows T*16.., cols ct*16..

__device__ __forceinline__ void gemm_core(const __half* ut, const short* Bh, const short* Bl,
                                          int w, int lane, f32x4 acc[2][2]){
  int r15 = lane & 15, q = lane >> 4;
  const short8v* BH = (const short8v*)Bh;
  const short8v* BL = (const short8v*)Bl;
  #pragma unroll
  for (int kt=0; kt<4; kt++){
    short8v ah[2], al[2];
    #pragma unroll
    for (int T=0;T<2;T++){
      int row = T*16 + r15;
      unsigned byte = (unsigned)(row*256 + kt*64 + q*16) ^ (unsigned)((row&7)<<4);
      short8v hv = *(const short8v*)((const char*)ut + byte);
      #pragma unroll
      for (int i=0;i<8;i++){
        float f = __half2float(__builtin_bit_cast(__half,(unsigned short)hv[i]));
        unsigned short hb = f2bf(f);
        ah[T][i] = (short)hb;
        al[T][i] = (short)f2bf(f - bf2f(hb));
      }
    }
    #pragma unroll
    for (int c=0;c<2;c++){
      int ct = w*2 + c;
      short8v bh = BH[(kt*8+ct)*64 + lane];
      short8v bl = BL[(kt*8+ct)*64 + lane];
      #pragma unroll
      for (int T=0;T<2;T++){
        acc[T][c] = __builtin_amdgcn_mfma_f32_16x16x32_bf16(ah[T], bh, acc[T][c], 0,0,0);
        acc[T][c] = __builtin_amdgcn_mfma_f32_16x16x32_bf16(al[T], bh, acc[T][c], 0,0,0);
        acc[T][c] = __builtin_amdgcn_mfma_f32_16x16x32_bf16(ah[T], bl, acc[T][c], 0,0,0);
      }
    }
  }
}

__device__ __forceinline__ void lds_store_row(__half* ut, int r, int lane, float2 a){
  unsigned byte = (unsigned)(r*256 + lane*4) ^ (unsigned)((r&7)<<4);
  *(__half2*)((char*)ut + byte) = __float22half2_rn(a);
}

// ---------- layer 1 fused: agg in emb space (embh 2.56MB L2-resident) + GEMM(W1) ----------

__global__ __launch_bounds__(256) void k_l1(const int* __restrict__ feat, const __half* __restrict__ embh,
      const unsigned short* __restrict__ eSrc, const int* __restrict__ rowStart,
      const int* __restrict__ deg, const float* __restrict__ dinv,
      const short* __restrict__ Bh, const short* __restrict__ Bl,
      const float* __restrict__ bias, __half* __restrict__ xout){
  __shared__ __half ut[32*C];
  int t = threadIdx.x, w = t>>6, lane = t&63;
  int node0 = blockIdx.x*32;
  const __half2* E = (const __half2*)embh;
  #pragma unroll
  for (int rr=0; rr<8; rr++){
    int r = w*8 + rr;
    int node = node0 + r;
    float2 a = make_float2(0.f,0.f);
    if (node < N_NODES){
      int rs = rowStart[node], len = deg[node];
      float dn = dinv[node];
      float2 sv = __half22float2(E[(size_t)feat[node]*64 + lane]);
      a.x = dn*sv.x; a.y = dn*sv.y;
      int k=0;
      for (; k+4<=len; k+=4){
        int s0=eSrc[rs+k], s1=eSrc[rs+k+1], s2=eSrc[rs+k+2], s3=eSrc[rs+k+3];
        int f0=feat[s0], f1=feat[s1], f2=feat[s2], f3=feat[s3];
        float d0=dinv[s0], d1=dinv[s1], d2=dinv[s2], d3=dinv[s3];
        float2 v0=__half22float2(E[(size_t)f0*64+lane]);
        float2 v1=__half22float2(E[(size_t)f1*64+lane]);
        float2 v2=__half22float2(E[(size_t)f2*64+lane]);
        float2 v3=__half22float2(E[(size_t)f3*64+lane]);
        a.x=fmaf(d0,v0.x,a.x); a.y=fmaf(d0,v0.y,a.y);
        a.x=fmaf(d1,v1.x,a.x); a.y=fmaf(d1,v1.y,a.y);
        a.x=fmaf(d2,v2.x,a.x); a.y=fmaf(d2,v2.y,a.y);
        a.x=fmaf(d3,v3.x,a.x); a.y=fmaf(d3,v3.y,a.y);
      }
      for (; k<len; k++){
        int s0=eSrc[rs+k];
        float dd=dinv[s0];
        float2 v=__half22float2(E[(size_t)feat[s0]*64+lane]);
        a.x=fmaf(dd,v.x,a.x); a.y=fmaf(dd,v.y,a.y);
      }
      a.x*=dn; a.y*=dn;
    }
    lds_store_row(ut, r, lane, a);
  }
  __syncthreads();
  f32x4 acc[2][2];
  #pragma unroll
  for (int T=0;T<2;T++){ acc[T][0]=(f32x4){0,0,0,0}; acc[T][1]=(f32x4){0,0,0,0}; }
  gemm_core(ut, Bh, Bl, w, lane, acc);
  int r15 = lane&15, q = lane>>4;
  float bb[2] = { bias[(w*2)*16+r15], bias[(w*2+1)*16+r15] };
  #pragma unroll
  for (int T=0;T<2;T++){
    #pragma unroll
    for (int j=0;j<4;j++){
      int rz = node0 + T*16 + q*4 + j;
      if (rz < N_NODES){
        float d = dinv[rz];
        #pragma unroll
        for (int c=0;c<2;c++){
          float v = fmaxf(acc[T][c][j] + bb[c], 0.f);
          xout[(size_t)rz*C + (w*2+c)*16 + r15] = __float2half(v*d);
        }
      }
    }
  }
}

// ---------- layer 2 fused: agg in xs space + GEMM(W2) ----------

__global__ __launch_bounds__(256) void k_l2(const __half* __restrict__ xin,
      const unsigned short* __restrict__ eSrc, const int* __restrict__ rowStart,
      const int* __restrict__ deg, const float* __restrict__ dinv,
      const short* __restrict__ Bh, const short* __restrict__ Bl,
      const float* __restrict__ bias, __half* __restrict__ xout){
  __shared__ __half ut[32*C];
  int t = threadIdx.x, w = t>>6, lane = t&63;
  int node0 = blockIdx.x*32;
  const __half2* zb = (const __half2*)xin;
  #pragma unroll
  for (int rr=0; rr<8; rr++){
    int r = w*8 + rr;
    int node = node0 + r;
    float2 a = make_float2(0.f,0.f);
    if (node < N_NODES){
      int rs = rowStart[node], len = deg[node];
      a = __half22float2(zb[(size_t)node*64 + lane]);
      int k=0;
      for (; k+4<=len; k+=4){
        int s0=eSrc[rs+k], s1=eSrc[rs+k+1], s2=eSrc[rs+k+2], s3=eSrc[rs+k+3];
        float2 v0=__half22float2(zb[(size_t)s0*64+lane]);
        float2 v1=__half22float2(zb[(size_t)s1*64+lane]);
        float2 v2=__half22float2(zb[(size_t)s2*64+lane]);
        float2 v3=__half22float2(zb[(size_t)s3*64+lane]);
        a.x += v0.x+v1.x+v2.x+v3.x;
        a.y += v0.y+v1.y+v2.y+v3.y;
      }
      for (; k<len; k++){
        float2 v=__half22float2(zb[(size_t)eSrc[rs+k]*64+lane]);
        a.x+=v.x; a.y+=v.y;
      }
      float dn = dinv[node];
      a.x*=dn; a.y*=dn;
    }
    lds_store_row(ut, r, lane, a);
  }
  __syncthreads();
  f32x4 acc[2][2];
  #pragma unroll
  for (int T=0;T<2;T++){ acc[T][0]=(f32x4){0,0,0,0}; acc[T][1]=(f32x4){0,0,0,0}; }
  gemm_core(ut, Bh, Bl, w, lane, acc);
  int r15 = lane&15, q = lane>>4;
  float bb[2] = { bias[(w*2)*16+r15], bias[(w*2+1)*16+r15] };
  #pragma unroll
  for (int T=0;T<2;T++){
    #pragma unroll
    for (int j=0;j<4;j++){
      int rz = node0 + T*16 + q*4 + j;
      if (rz < N_NODES){
        float d = dinv[rz];
        #pragma unroll
        for (int c=0;c<2;c++){
          float v = fmaxf(acc[T][c][j] + bb[c], 0.f);
          xout[(size_t)rz*C + (w*2+c)*16 + r15] = __float2half(v*d);
        }
      }
    }
  }
}

// ---------- layer 3 fused: agg + GEMM(W3) + fcW dot -> dots ----------

__global__ __launch_bounds__(256) void k_l3(const __half* __restrict__ xin,
      const unsigned short* __restrict__ eSrc, const int* __restrict__ rowStart,
      const int* __restrict__ deg, const float* __restrict__ dinv,
      const short* __restrict__ Bh, const short* __restrict__ Bl,
      const float* __restrict__ bias, const float* __restrict__ fcW,
      float* __restrict__ dots){
  __shared__ __half ut[32*C];
  __shared__ float dotb[32][4];
  int t = threadIdx.x, w = t>>6, lane = t&63;
  int node0 = blockIdx.x*32;
  const __half2* zb = (const __half2*)xin;
  #pragma unroll
  for (int rr=0; rr<8; rr++){
    int r = w*8 + rr;
    int node = node0 + r;
    float2 a = make_float2(0.f,0.f);
    if (node < N_NODES){
      int rs = rowStart[node], len = deg[node];
      a = __half22float2(zb[(size_t)node*64 + lane]);
      int k=0;
      for (; k+4<=len; k+=4){
        int s0=eSrc[rs+k], s1=eSrc[rs+k+1], s2=eSrc[rs+k+2], s3=eSrc[rs+k+3];
        float2 v0=__half22float2(zb[(size_t)s0*64+lane]);
        float2 v1=__half22float2(zb[(size_t)s1*64+lane]);
        float2 v2=__half22float2(zb[(size_t)s2*64+lane]);
        float2 v3=__half22float2(zb[(size_t)s3*64+lane]);
        a.x += v0.x+v1.x+v2.x+v3.x;
        a.y += v0.y+v1.y+v2.y+v3.y;
      }
      for (; k<len; k++){
        float2 v=__half22float2(zb[(size_t)eSrc[rs+k]*64+lane]);
        a.x+=v.x; a.y+=v.y;
      }
      float dn = dinv[node];
      a.x*=dn; a.y*=dn;
    }
    lds_store_row(ut, r, lane, a);
  }
  __syncthreads();
  f32x4 acc[2][2];
  #pragma unroll
  for (int T=0;T<2;T++){ acc[T][0]=(f32x4){0,0,0,0}; acc[T][1]=(f32x4){0,0,0,0}; }
  gemm_core(ut, Bh, Bl, w, lane, acc);
  int r15 = lane&15, q = lane>>4;
  float bb[2] = { bias[(w*2)*16+r15], bias[(w*2+1)*16+r15] };
  float fw[2] = { fcW[(w*2)*16+r15],  fcW[(w*2+1)*16+r15] };
  #pragma unroll
  for (int T=0;T<2;T++){
    #pragma unroll
    for (int j=0;j<4;j++){
      float s = fmaxf(acc[T][0][j] + bb[0], 0.f)*fw[0]
              + fmaxf(acc[T][1][j] + bb[1], 0.f)*fw[1];
      s += __shfl_xor(s, 1);
      s += __shfl_xor(s, 2);
      s += __shfl_xor(s, 4);
      s += __shfl_xor(s, 8);
      if (r15 == 0) dotb[T*16 + q*4 + j][w] = s;
    }
  }
  __syncthreads();
  if (t < 32){
    int node = node0 + t;
    if (node < N_NODES)
      dots[node] = dotb[t][0] + dotb[t][1] + dotb[t][2] + dotb[t][3];
  }
}

// ---------- pooling ----------

__global__ void k_pool_seg(const float* __restrict__ dots, const int* __restrict__ gStart,
                           const float* __restrict__ fcb, float* __restrict__ out){
  __shared__ float s[256];
  int g = blockIdx.x;
  int st = gStart[g], en = gStart[g+1];
  float acc = 0.f;
  for (int i = st + threadIdx.x; i < en; i += 256) acc += dots[i];
  s[threadIdx.x] = acc; __syncthreads();
  for (int off=128; off>0; off>>=1){
    if (threadIdx.x < off) s[threadIdx.x] += s[threadIdx.x+off];
    __syncthreads();
  }
  if (threadIdx.x==0) out[g] = s[0]/fmaxf((float)(en-st),1.0f) + fcb[0];
}

// ---------- launch ----------

extern "C" void kernel_launch(void* const* d_in, const int* in_sizes, int n_in,
                              void* d_out, int out_size, void* d_ws, size_t ws_size,
                              hipStream_t stream){
  const int* edge  = (const int*)d_in[0];
  const int* srcI  = edge;
  const int* dstI  = edge + N_EDGES;
  const int* feat  = (const int*)d_in[1];
  const int* batch = (const int*)d_in[2];
  const float* emb = (const float*)d_in[3];
  const float* W1  = (const float*)d_in[4];
  const float* b1  = (const float*)d_in[5];
  const float* W2  = (const float*)d_in[6];
  const float* b2  = (const float*)d_in[7];
  const float* W3  = (const float*)d_in[8];
  const float* b3  = (const float*)d_in[9];
  const float* fcW = (const float*)d_in[10];
  const float* fcb = (const float*)d_in[11];
  float* out = (float*)d_out;

  __half* xsA = (__half*)d_ws;                       // 50000*128 f16
  __half* xsB = xsA + (size_t)N_NODES*C;             // 50000*128 f16
  __half* embh = xsB + (size_t)N_NODES*C;            // 10000*128 f16
  unsigned* binned = (unsigned*)(embh + (size_t)VOCAB*C); // 800000 u32
  unsigned short* eSrc  = (unsigned short*)(binned + N_EDGES);  // 800000 u16
  int* rowStart = (int*)(eSrc + N_EDGES);            // 50000
  int* deg      = rowStart + N_NODES;                // 50000
  float* dinv   = (float*)(deg + N_NODES);           // 50000
  int* blockHist = (int*)(dinv + N_NODES);           // 200*256
  int* blockOfs  = blockHist + A_BLOCKS*256;         // 200*256
  int* bucketBase = blockOfs + A_BLOCKS*256;         // 257 (+pad)
  int* gStart     = bucketBase + 260;                // 513 (+pad)
  float* dots   = (float*)(gStart + 520);            // 50000
  short* Bpack  = (short*)(dots + N_NODES);          // 6*16384 shorts
  short* Bh1 = Bpack,           * Bl1 = Bpack + 16384;
  short* Bh2 = Bpack + 2*16384, * Bl2 = Bpack + 3*16384;
  short* Bh3 = Bpack + 4*16384, * Bl3 = Bpack + 5*16384;

  k_binCount  <<<A_BLOCKS, 256, 0, stream>>>(dstI, blockHist);
  k_binScan   <<<1, 256, 0, stream>>>(blockHist, blockOfs, bucketBase);
  k_binScatter<<<A_BLOCKS, 256, 0, stream>>>(srcI, dstI, bucketBase, blockOfs, binned);
  k_binFinal  <<<NBUCK, 256, 0, stream>>>(binned, bucketBase, eSrc, rowStart, deg, dinv);
  k_prep      <<<NBUCK+24+64, 256, 0, stream>>>(batch, gStart, W1, W2, W3, Bpack, emb, embh);

  int LBLOCKS = (N_NODES + 31)/32;   // 1563
  k_l1<<<LBLOCKS, 256, 0, stream>>>(feat, embh, eSrc, rowStart, deg, dinv, Bh1, Bl1, b1, xsB);
  k_l2<<<LBLOCKS, 256, 0, stream>>>(xsB, eSrc, rowStart, deg, dinv, Bh2, Bl2, b2, xsA);
  k_l3<<<LBLOCKS, 256, 0, stream>>>(xsA, eSrc, rowStart, deg, dinv, Bh3, Bl3, b3, fcW, dots);

  k_pool_seg<<<N_GRAPHS, 256, 0, stream>>>(dots, gStart, fcb, out);
}

// Round 9
// 210.811 us; speedup vs baseline: 1.3274x; 1.3274x over previous
//
#include <hip/hip_runtime.h>
#include <hip/hip_fp16.h>

#define N_NODES 50000
#define N_EDGES 800000
#define N_GRAPHS 512
#define VOCAB 10000
#define C 128
#define NBUCK 196            // ceil(50000/256), bucket = dst>>8
#define A_BLOCKS 200         // 4000 edges each
#define EDGES_PER_A (N_EDGES / A_BLOCKS)
#define SE_CAP 8192          // LDS eSrc staging per bucket (mean 4096)

typedef __attribute__((ext_vector_type(8))) short short8v;
typedef __attribute__((ext_vector_type(4))) float f32x4;

__device__ __forceinline__ unsigned short f2bf(float f){
  unsigned u = __builtin_bit_cast(unsigned, f);
  unsigned r = u + 0x7FFFu + ((u >> 16) & 1u);
  return (unsigned short)(r >> 16);
}
__device__ __forceinline__ float bf2f(unsigned short h){
  unsigned u = ((unsigned)h) << 16;
  return __builtin_bit_cast(float, u);
}

// ---------- binning A1: per-block bucket histograms ----------
__global__ __launch_bounds__(256) void k_binCount(const int* __restrict__ dst, int* __restrict__ blockHist){
  __shared__ int h[256];
  int t = threadIdx.x;
  h[t] = 0; __syncthreads();
  int base = blockIdx.x * EDGES_PER_A;
  for (int i = t; i < EDGES_PER_A; i += 256)
    atomicAdd(&h[dst[base+i] >> 8], 1);
  __syncthreads();
  blockHist[blockIdx.x*256 + t] = h[t];
}

// ---------- scan: bucketBase + per-block chunk offsets ----------
__global__ void k_binScan(const int* __restrict__ blockHist, int* __restrict__ blockOfs,
                          int* __restrict__ bucketBase){
  __shared__ int s[256];
  int t = threadIdx.x;
  int run = 0;
  for (int b = 0; b < A_BLOCKS; b++){
    int v = blockHist[b*256 + t];
    blockOfs[b*256 + t] = run;
    run += v;
  }
  s[t] = run; __syncthreads();
  for (int off=1; off<256; off<<=1){
    int u = (t>=off) ? s[t-off] : 0;
    __syncthreads();
    s[t] += u;
    __syncthreads();
  }
  bucketBase[t+1] = s[t];
  if (t == 0) bucketBase[0] = 0;
}

// ---------- binning A2: scatter packed edges (no global atomics) ----------
__global__ __launch_bounds__(256) void k_binScatter(const int* __restrict__ src, const int* __restrict__ dst,
                           const int* __restrict__ bucketBase, const int* __restrict__ blockOfs,
                           unsigned* __restrict__ binned){
  __shared__ int ofs[256], cur[256];
  int t = threadIdx.x;
  ofs[t] = bucketBase[t] + blockOfs[blockIdx.x*256 + t];
  cur[t] = 0;
  __syncthreads();
  int base = blockIdx.x * EDGES_PER_A;
  for (int i = t; i < EDGES_PER_A; i += 256){
    int d = dst[base+i];
    int b = d >> 8;
    int p = atomicAdd(&cur[b], 1);
    binned[ofs[b] + p] = (unsigned)(src[base+i] & 0xFFFF) | ((unsigned)(d & 0xFF) << 16);
  }
}

// ---------- binning B: per-bucket CSR finalize ----------
__global__ __launch_bounds__(256) void k_binFinal(const unsigned* __restrict__ binned,
                         const int* __restrict__ bucketBase,
                         unsigned short* __restrict__ eSrc, int* __restrict__ rowStart,
                         int* __restrict__ deg, float* __restrict__ dinv){
  __shared__ int h[256], pre[256], cur[256];
  __shared__ unsigned short sE[SE_CAP];
  int b = blockIdx.x;
  int t = threadIdx.x;
  int base = bucketBase[b], cnt = bucketBase[b+1] - base;
  int nodeBase = b << 8;
  h[t] = 0; __syncthreads();
  for (int i = t; i < cnt; i += 256)
    atomicAdd(&h[binned[base+i] >> 16], 1);
  __syncthreads();
  pre[t] = h[t]; __syncthreads();
  for (int off=1; off<256; off<<=1){
    int u = (t>=off) ? pre[t-off] : 0;
    __syncthreads();
    pre[t] += u;
    __syncthreads();
  }
  int node = nodeBase + t;
  if (node < N_NODES){
    int d = h[t];
    deg[node] = d;
    rowStart[node] = base + pre[t] - d;
    dinv[node] = rsqrtf((float)d + 1.0f);
  }
  cur[t] = pre[t] - h[t];
  __syncthreads();
  for (int i = t; i < cnt; i += 256){
    unsigned v = binned[base+i];
    int dl = v >> 16;
    int p = atomicAdd(&cur[dl], 1);
    unsigned short s = (unsigned short)(v & 0xFFFF);
    if (p < SE_CAP) sE[p] = s;
    else eSrc[base + p] = s;
  }
  __syncthreads();
  int lim = cnt < SE_CAP ? cnt : SE_CAP;
  for (int i = t; i < lim; i += 256) eSrc[base+i] = sE[i];
}

// ---------- prep: gstart | W-prepack | emb->fp16 | per-edge (feat,dinv) ----------
__global__ __launch_bounds__(256) void k_prep(const int* __restrict__ batch, int* __restrict__ gStart,
                       const float* __restrict__ W1, const float* __restrict__ W2,
                       const float* __restrict__ W3, short* __restrict__ Bp,
                       const float* __restrict__ emb, __half* __restrict__ embh,
                       const unsigned short* __restrict__ eSrc, const int* __restrict__ feat,
                       const float* __restrict__ dinv,
                       unsigned short* __restrict__ eFeat, float* __restrict__ eDinv){
  int b = blockIdx.x, t = threadIdx.x;
  if (b < NBUCK){                       // gstart
    int i = b*256 + t;
    if (i >= N_NODES) return;
    int bb = batch[i];
    int pb = (i==0) ? -1 : batch[i-1];
    for (int g=pb+1; g<=bb; g++) gStart[g] = i;
    if (i == N_NODES-1)
      for (int g=bb+1; g<=N_GRAPHS; g++) gStart[g] = N_NODES;
  } else if (b < NBUCK+24){             // W prepack (3 layers x 2048 threads)
    int idx = (b-NBUCK)*256 + t;        // 0..6143
    int layer = idx / 2048;
    int r = idx - layer*2048;
    const float* W = (layer==0) ? W1 : (layer==1) ? W2 : W3;
    short* Bh = Bp + (size_t)layer*32768;
    short* Bl = Bh + 16384;
    int lane = r & 63, tile = r >> 6;   // tile = kt*8 + ct
    int kt = tile >> 3, ct = tile & 7;
    int q = lane >> 4, c = ct*16 + (lane & 15);
    #pragma unroll
    for (int i=0;i<8;i++){
      int k = kt*32 + q*8 + i;
      float w = W[k*C + c];
      unsigned short hh = f2bf(w);
      unsigned short ll = f2bf(w - bf2f(hh));
      Bh[(size_t)(tile*64 + lane)*8 + i] = (short)hh;
      Bl[(size_t)(tile*64 + lane)*8 + i] = (short)ll;
    }
  } else if (b < NBUCK+24+64){          // emb -> fp16
    int idx = (b-NBUCK-24)*256 + t;
    const float2* s = (const float2*)emb;
    __half2* d2 = (__half2*)embh;
    for (int i = idx; i < VOCAB*C/2; i += 64*256)
      d2[i] = __float22half2_rn(s[i]);
  } else {                              // per-edge metadata (200 blocks)
    int idx = (b-NBUCK-24-64)*256 + t;
    for (int e = idx; e < N_EDGES; e += 200*256){
      int s = eSrc[e];
      eFeat[e] = (unsigned short)feat[s];
      eDinv[e] = dinv[s];
    }
  }
}

// ---------- agg layer 1 (embedding space, L2-resident table), MLP=8 ----------
// u[i] = fp16( dinv_i * ( dinv_i*embh[feat_i] + sum_e eDinv[e]*embh[eFeat[e]] ) )

__global__ __launch_bounds__(256) void k_agg1(const __half* __restrict__ embh,
                      const unsigned short* __restrict__ eFeat, const float* __restrict__ eDinv,
                      const int* __restrict__ rowStart, const int* __restrict__ deg,
                      const float* __restrict__ dinv, const int* __restrict__ feat,
                      __half* __restrict__ uout){
  int node = blockIdx.x*4 + (threadIdx.x>>6);
  int lane = threadIdx.x & 63;
  if (node >= N_NODES) return;
  int rs = rowStart[node], len = deg[node];
  float dn = dinv[node];
  const __half2* E = (const __half2*)embh;   // row stride 64 half2
  float2 sv = __half22float2(E[(size_t)feat[node]*64 + lane]);
  float2 a = make_float2(dn*sv.x, dn*sv.y);
  int k = 0;
  for (; k+8<=len; k+=8){
    int f[8]; float dd[8];
    #pragma unroll
    for (int j=0;j<8;j++){ f[j] = eFeat[rs+k+j]; dd[j] = eDinv[rs+k+j]; }
    float2 v[8];
    #pragma unroll
    for (int j=0;j<8;j++) v[j] = __half22float2(E[(size_t)f[j]*64 + lane]);
    #pragma unroll
    for (int j=0;j<8;j++){ a.x = fmaf(dd[j], v[j].x, a.x); a.y = fmaf(dd[j], v[j].y, a.y); }
  }
  for (; k+4<=len; k+=4){
    int f0=eFeat[rs+k], f1=eFeat[rs+k+1], f2=eFeat[rs+k+2], f3=eFeat[rs+k+3];
    float d0=eDinv[rs+k], d1=eDinv[rs+k+1], d2=eDinv[rs+k+2], d3=eDinv[rs+k+3];
    float2 v0=__half22float2(E[(size_t)f0*64+lane]);
    float2 v1=__half22float2(E[(size_t)f1*64+lane]);
    float2 v2=__half22float2(E[(size_t)f2*64+lane]);
    float2 v3=__half22float2(E[(size_t)f3*64+lane]);
    a.x=fmaf(d0,v0.x,a.x); a.y=fmaf(d0,v0.y,a.y);
    a.x=fmaf(d1,v1.x,a.x); a.y=fmaf(d1,v1.y,a.y);
    a.x=fmaf(d2,v2.x,a.x); a.y=fmaf(d2,v2.y,a.y);
    a.x=fmaf(d3,v3.x,a.x); a.y=fmaf(d3,v3.y,a.y);
  }
  for (; k<len; k++){
    float dd = eDinv[rs+k];
    float2 v = __half22float2(E[(size_t)eFeat[rs+k]*64 + lane]);
    a.x = fmaf(dd, v.x, a.x); a.y = fmaf(dd, v.y, a.y);
  }
  ((__half2*)uout)[(size_t)node*64 + lane] = __float22half2_rn(make_float2(dn*a.x, dn*a.y));
}

// ---------- agg layers 2-3 (xs space), MLP=8: u[i] = fp16( dinv_i*(xs_i + sum xs_src) ) ----------

__global__ __launch_bounds__(256) void k_aggS(const __half* __restrict__ xs, const unsigned short* __restrict__ eSrc,
                      const int* __restrict__ rowStart, const int* __restrict__ deg,
                      const float* __restrict__ dinv, __half* __restrict__ uout){
  int node = blockIdx.x*4 + (threadIdx.x>>6);
  int lane = threadIdx.x & 63;
  if (node >= N_NODES) return;
  int rs = rowStart[node], len = deg[node];
  const __half2* zb = (const __half2*)xs;
  float2 a = __half22float2(zb[(size_t)node*64 + lane]);
  int k = 0;
  for (; k+8<=len; k+=8){
    int s[8];
    #pragma unroll
    for (int j=0;j<8;j++) s[j] = eSrc[rs+k+j];
    float2 v[8];
    #pragma unroll
    for (int j=0;j<8;j++) v[j] = __half22float2(zb[(size_t)s[j]*64 + lane]);
    #pragma unroll
    for (int j=0;j<8;j++){ a.x += v[j].x; a.y += v[j].y; }
  }
  for (; k+4<=len; k+=4){
    int s0=eSrc[rs+k], s1=eSrc[rs+k+1], s2=eSrc[rs+k+2], s3=eSrc[rs+k+3];
    float2 v0=__half22float2(zb[(size_t)s0*64+lane]);
    float2 v1=__half22float2(zb[(size_t)s1*64+lane]);
    float2 v2=__half22float2(zb[(size_t)s2*64+lane]);
    float2 v3=__half22float2(zb[(size_t)s3*64+lane]);
    a.x += v0.x+v1.x+v2.x+v3.x;
    a.y += v0.y+v1.y+v2.y+v3.y;
  }
  for (; k<len; k++){
    float2 v = __half22float2(zb[(size_t)eSrc[rs+k]*64 + lane]);
    a.x += v.x; a.y += v.y;
  }
  float dn = dinv[node];
  ((__half2*)uout)[(size_t)node*64 + lane] = __float22half2_rn(make_float2(dn*a.x, dn*a.y));
}

// ---------- MFMA body shared by both gemm kernels (A = fp16 u, split-bf16 exact) ----------

#define GEMM_BODY(XR0, XR1) \
  f32x4 acc[2][8]; \
  _Pragma("unroll") for (int T=0;T<2;T++) \
    _Pragma("unroll") for (int ct=0;ct<8;ct++) acc[T][ct] = (f32x4){0.f,0.f,0.f,0.f}; \
  const short8v* BH = (const short8v*)Bh; \
  const short8v* BL = (const short8v*)Bl; \
  _Pragma("unroll") \
  for (int kt=0; kt<4; kt++){ \
    short8v ah0, al0, ah1, al1; \
    { short8v hv = *(const short8v*)(XR0 + kt*32 + q*8); \
      _Pragma("unroll") for (int i=0;i<8;i++){ \
        float f = __half2float(__builtin_bit_cast(__half, (unsigned short)hv[i])); \
        unsigned short hb = f2bf(f); ah0[i] = (short)hb; al0[i] = (short)f2bf(f - bf2f(hb)); } } \
    { short8v hv = *(const short8v*)(XR1 + kt*32 + q*8); \
      _Pragma("unroll") for (int i=0;i<8;i++){ \
        float f = __half2float(__builtin_bit_cast(__half, (unsigned short)hv[i])); \
        unsigned short hb = f2bf(f); ah1[i] = (short)hb; al1[i] = (short)f2bf(f - bf2f(hb)); } } \
    _Pragma("unroll") \
    for (int ct=0; ct<8; ct++){ \
      short8v bh = BH[(kt*8+ct)*64 + lane]; \
      short8v bl = BL[(kt*8+ct)*64 + lane]; \
      acc[0][ct] = __builtin_amdgcn_mfma_f32_16x16x32_bf16(ah0, bh, acc[0][ct], 0, 0, 0); \
      acc[0][ct] = __builtin_amdgcn_mfma_f32_16x16x32_bf16(al0, bh, acc[0][ct], 0, 0, 0); \
      acc[0][ct] = __builtin_amdgcn_mfma_f32_16x16x32_bf16(ah0, bl, acc[0][ct], 0, 0, 0); \
      acc[1][ct] = __builtin_amdgcn_mfma_f32_16x16x32_bf16(ah1, bh, acc[1][ct], 0, 0, 0); \
      acc[1][ct] = __builtin_amdgcn_mfma_f32_16x16x32_bf16(al1, bh, acc[1][ct], 0, 0, 0); \
      acc[1][ct] = __builtin_amdgcn_mfma_f32_16x16x32_bf16(ah1, bl, acc[1][ct], 0, 0, 0); \
    } \
  }

// ---------- gemm layers 1-2: xs = fp16( dinv * relu(u@W + b) ) ----------

__global__ __launch_bounds__(256) void k_gemmA(
            const __half* __restrict__ uin,
            const short* __restrict__ Bh, const short* __restrict__ Bl,
            const float* __restrict__ bias, const float* __restrict__ dinv,
            __half* __restrict__ xs){
  int lane = threadIdx.x & 63;
  int pb = blockIdx.x*4 + (threadIdx.x >> 6);
  int R0 = pb*32;
  if (R0 >= N_NODES) return;
  int r15 = lane & 15, q = lane >> 4;
  int row0 = R0 + r15;        if (row0 >= N_NODES) row0 = N_NODES-1;
  int row1 = R0 + 16 + r15;   if (row1 >= N_NODES) row1 = N_NODES-1;
  const __half* xr0 = uin + (size_t)row0*C;
  const __half* xr1 = uin + (size_t)row1*C;
  GEMM_BODY(xr0, xr1)
  float bb[8];
  #pragma unroll
  for (int ct=0;ct<8;ct++) bb[ct] = bias[ct*16 + r15];
  #pragma unroll
  for (int T=0;T<2;T++){
    #pragma unroll
    for (int j=0;j<4;j++){
      int rz = R0 + T*16 + q*4 + j;
      if (rz < N_NODES){
        float d = dinv[rz];
        #pragma unroll
        for (int ct=0; ct<8; ct++){
          float v = fmaxf(acc[T][ct][j] + bb[ct], 0.f);
          xs[(size_t)rz*C + ct*16 + r15] = __float2half(v * d);
        }
      }
    }
  }
}

// ---------- gemm layer 3: dots[i] = relu(u@W3 + b3) . fcW ----------

__global__ __launch_bounds__(256) void k_gemm3(
            const __half* __restrict__ uin,
            const short* __restrict__ Bh, const short* __restrict__ Bl,
            const float* __restrict__ bias, const float* __restrict__ fcW,
            float* __restrict__ dots){
  int lane = threadIdx.x & 63;
  int pb = blockIdx.x*4 + (threadIdx.x >> 6);
  int R0 = pb*32;
  if (R0 >= N_NODES) return;
  int r15 = lane & 15, q = lane >> 4;
  int row0 = R0 + r15;        if (row0 >= N_NODES) row0 = N_NODES-1;
  int row1 = R0 + 16 + r15;   if (row1 >= N_NODES) row1 = N_NODES-1;
  const __half* xr0 = uin + (size_t)row0*C;
  const __half* xr1 = uin + (size_t)row1*C;
  GEMM_BODY(xr0, xr1)
  float bb[8], fw[8];
  #pragma unroll
  for (int ct=0;ct<8;ct++){ bb[ct] = bias[ct*16 + r15]; fw[ct] = fcW[ct*16 + r15]; }
  #pragma unroll
  for (int T=0;T<2;T++){
    #pragma unroll
    for (int j=0;j<4;j++){
      int rz = R0 + T*16 + q*4 + j;
      float s = 0.f;
      #pragma unroll
      for (int ct=0; ct<8; ct++)
        s += fmaxf(acc[T][ct][j] + bb[ct], 0.f) * fw[ct];
      s += __shfl_xor(s, 1);
      s += __shfl_xor(s, 2);
      s += __shfl_xor(s, 4);
      s += __shfl_xor(s, 8);
      if (r15 == 0 && rz < N_NODES) dots[rz] = s;
    }
  }
}

// ---------- pooling ----------

__global__ void k_pool_seg(const float* __restrict__ dots, const int* __restrict__ gStart,
                           const float* __restrict__ fcb, float* __restrict__ out){
  __shared__ float s[256];
  int g = blockIdx.x;
  int st = gStart[g], en = gStart[g+1];
  float acc = 0.f;
  for (int i = st + threadIdx.x; i < en; i += 256) acc += dots[i];
  s[threadIdx.x] = acc; __syncthreads();
  for (int off=128; off>0; off>>=1){
    if (threadIdx.x < off) s[threadIdx.x] += s[threadIdx.x+off];
    __syncthreads();
  }
  if (threadIdx.x==0) out[g] = s[0]/fmaxf((float)(en-st),1.0f) + fcb[0];
}

// ---------- launch ----------

extern "C" void kernel_launch(void* const* d_in, const int* in_sizes, int n_in,
                              void* d_out, int out_size, void* d_ws, size_t ws_size,
                              hipStream_t stream){
  const int* edge  = (const int*)d_in[0];
  const int* srcI  = edge;
  const int* dstI  = edge + N_EDGES;
  const int* feat  = (const int*)d_in[1];
  const int* batch = (const int*)d_in[2];
  const float* emb = (const float*)d_in[3];
  const float* W1  = (const float*)d_in[4];
  const float* b1  = (const float*)d_in[5];
  const float* W2  = (const float*)d_in[6];
  const float* b2  = (const float*)d_in[7];
  const float* W3  = (const float*)d_in[8];
  const float* b3  = (const float*)d_in[9];
  const float* fcW = (const float*)d_in[10];
  const float* fcb = (const float*)d_in[11];
  float* out = (float*)d_out;

  __half* bufA = (__half*)d_ws;                      // u   50000*128 f16
  __half* bufB = bufA + (size_t)N_NODES*C;           // xs  50000*128 f16
  __half* embh = bufB + (size_t)N_NODES*C;           // 10000*128 f16
  unsigned* binned = (unsigned*)(embh + (size_t)VOCAB*C); // 800000 u32
  unsigned short* eSrc  = (unsigned short*)(binned + N_EDGES);  // 800000 u16
  unsigned short* eFeat = eSrc + N_EDGES;            // 800000 u16
  float* eDinv  = (float*)(eFeat + N_EDGES);         // 800000 f32
  int* rowStart = (int*)(eDinv + N_EDGES);           // 50000
  int* deg      = rowStart + N_NODES;                // 50000
  float* dinv   = (float*)(deg + N_NODES);           // 50000
  int* blockHist = (int*)(dinv + N_NODES);           // 200*256
  int* blockOfs  = blockHist + A_BLOCKS*256;         // 200*256
  int* bucketBase = blockOfs + A_BLOCKS*256;         // 257 (+pad)
  int* gStart     = bucketBase + 260;                // 513 (+pad)
  float* dots   = (float*)(gStart + 520);            // 50000
  short* Bpack  = (short*)(dots + N_NODES);          // 6*16384 shorts
  short* Bh1 = Bpack,           * Bl1 = Bpack + 16384;
  short* Bh2 = Bpack + 2*16384, * Bl2 = Bpack + 3*16384;
  short* Bh3 = Bpack + 4*16384, * Bl3 = Bpack + 5*16384;

  k_binCount  <<<A_BLOCKS, 256, 0, stream>>>(dstI, blockHist);
  k_binScan   <<<1, 256, 0, stream>>>(blockHist, blockOfs, bucketBase);
  k_binScatter<<<A_BLOCKS, 256, 0, stream>>>(srcI, dstI, bucketBase, blockOfs, binned);
  k_binFinal  <<<NBUCK, 256, 0, stream>>>(binned, bucketBase, eSrc, rowStart, deg, dinv);
  k_prep      <<<NBUCK+24+64+200, 256, 0, stream>>>(batch, gStart, W1, W2, W3, Bpack,
                                                    emb, embh, eSrc, feat, dinv, eFeat, eDinv);

  int aggBlocks  = (N_NODES+3)/4;         // 12500
  int gemmBlocks = (N_NODES + 127)/128;   // 391
  // layer 1: aggregate in embedding space (2.56MB working set), then GEMM
  k_agg1 <<<aggBlocks, 256, 0, stream>>>(embh, eFeat, eDinv, rowStart, deg, dinv, feat, bufA);
  k_gemmA<<<gemmBlocks, 256, 0, stream>>>(bufA, Bh1, Bl1, b1, dinv, bufB);
  // layer 2
  k_aggS <<<aggBlocks, 256, 0, stream>>>(bufB, eSrc, rowStart, deg, dinv, bufA);
  k_gemmA<<<gemmBlocks, 256, 0, stream>>>(bufA, Bh2, Bl2, b2, dinv, bufB);
  // layer 3: gemm emits per-node dot with fcW directly
  k_aggS <<<aggBlocks, 256, 0, stream>>>(bufB, eSrc, rowStart, deg, dinv, bufA);
  k_gemm3<<<gemmBlocks, 256, 0, stream>>>(bufA, Bh3, Bl3, b3, fcW, dots);

  k_pool_seg<<<N_GRAPHS, 256, 0, stream>>>(dots, gStart, fcb, out);
}

// Round 10
// 205.876 us; speedup vs baseline: 1.3592x; 1.0240x over previous
//
#include <hip/hip_runtime.h>
#include <hip/hip_fp16.h>

#define N_NODES 50000
#define N_EDGES 800000
#define N_GRAPHS 512
#define VOCAB 10000
#define C 128
#define NBUCK 196            // ceil(50000/256), bucket = dst>>8
#define A_BLOCKS 200         // 4000 edges each
#define EDGES_PER_A (N_EDGES / A_BLOCKS)
#define SE_CAP 8192          // LDS eSrc staging per bucket (mean 4096)

typedef __attribute__((ext_vector_type(8))) short short8v;
typedef __attribute__((ext_vector_type(4))) float f32x4;

__device__ __forceinline__ unsigned short f2bf(float f){
  unsigned u = __builtin_bit_cast(unsigned, f);
  unsigned r = u + 0x7FFFu + ((u >> 16) & 1u);
  return (unsigned short)(r >> 16);
}
__device__ __forceinline__ float bf2f(unsigned short h){
  unsigned u = ((unsigned)h) << 16;
  return __builtin_bit_cast(float, u);
}

// ---------- binning A1: per-block bucket histograms (bucket-major store) ----------
__global__ __launch_bounds__(256) void k_binCount(const int* __restrict__ dst, int* __restrict__ blockHist){
  __shared__ int h[256];
  int t = threadIdx.x;
  h[t] = 0; __syncthreads();
  int base = blockIdx.x * EDGES_PER_A;
  for (int i = t; i < EDGES_PER_A; i += 256)
    atomicAdd(&h[dst[base+i] >> 8], 1);
  __syncthreads();
  blockHist[t*A_BLOCKS + blockIdx.x] = h[t];   // bucket-major
}

// ---------- scan A: wave per bucket, prefix over 200 block entries ----------
__global__ __launch_bounds__(64) void k_binScanA(const int* __restrict__ blockHist,
                        int* __restrict__ blockOfs, int* __restrict__ bucketTot){
  int b = blockIdx.x;        // bucket (0..255)
  int l = threadIdx.x;       // lane
  int carry = 0;
  for (int c = 0; c < 256; c += 64){
    int idx = c + l;
    int v = (idx < A_BLOCKS) ? blockHist[b*A_BLOCKS + idx] : 0;
    int x = v;
    #pragma unroll
    for (int off=1; off<64; off<<=1){
      int y = __shfl_up(x, off);
      if (l >= off) x += y;
    }
    if (idx < A_BLOCKS) blockOfs[b*A_BLOCKS + idx] = carry + x - v;  // exclusive
    carry += __shfl(x, 63);
  }
  if (l == 0) bucketTot[b] = carry;
}

// ---------- scan B: exclusive scan of 256 bucket totals ----------
__global__ void k_binScanB(const int* __restrict__ bucketTot, int* __restrict__ bucketBase){
  __shared__ int s[256];
  int t = threadIdx.x;
  int v = bucketTot[t];
  s[t] = v; __syncthreads();
  for (int off=1; off<256; off<<=1){
    int u = (t>=off) ? s[t-off] : 0;
    __syncthreads();
    s[t] += u;
    __syncthreads();
  }
  bucketBase[t+1] = s[t];
  if (t == 0) bucketBase[0] = 0;
}

// ---------- binning A2: scatter packed edges (no global atomics) ----------
__global__ __launch_bounds__(256) void k_binScatter(const int* __restrict__ src, const int* __restrict__ dst,
                           const int* __restrict__ bucketBase, const int* __restrict__ blockOfs,
                           unsigned* __restrict__ binned){
  __shared__ int ofs[256], cur[256];
  int t = threadIdx.x;
  ofs[t] = bucketBase[t] + blockOfs[t*A_BLOCKS + blockIdx.x];
  cur[t] = 0;
  __syncthreads();
  int base = blockIdx.x * EDGES_PER_A;
  for (int i = t; i < EDGES_PER_A; i += 256){
    int d = dst[base+i];
    int b = d >> 8;
    int p = atomicAdd(&cur[b], 1);
    binned[ofs[b] + p] = (unsigned)(src[base+i] & 0xFFFF) | ((unsigned)(d & 0xFF) << 16);
  }
}

// ---------- binning B: per-bucket CSR finalize ----------
__global__ __launch_bounds__(256) void k_binFinal(const unsigned* __restrict__ binned,
                         const int* __restrict__ bucketBase,
                         unsigned short* __restrict__ eSrc, int* __restrict__ rowStart,
                         int* __restrict__ deg, float* __restrict__ dinv){
  __shared__ int h[256], pre[256], cur[256];
  __shared__ unsigned short sE[SE_CAP];
  int b = blockIdx.x;
  int t = threadIdx.x;
  int base = bucketBase[b], cnt = bucketBase[b+1] - base;
  int nodeBase = b << 8;
  h[t] = 0; __syncthreads();
  for (int i = t; i < cnt; i += 256)
    atomicAdd(&h[binned[base+i] >> 16], 1);
  __syncthreads();
  pre[t] = h[t]; __syncthreads();
  for (int off=1; off<256; off<<=1){
    int u = (t>=off) ? pre[t-off] : 0;
    __syncthreads();
    pre[t] += u;
    __syncthreads();
  }
  int node = nodeBase + t;
  if (node < N_NODES){
    int d = h[t];
    deg[node] = d;
    rowStart[node] = base + pre[t] - d;
    dinv[node] = rsqrtf((float)d + 1.0f);
  }
  cur[t] = pre[t] - h[t];
  __syncthreads();
  for (int i = t; i < cnt; i += 256){
    unsigned v = binned[base+i];
    int dl = v >> 16;
    int p = atomicAdd(&cur[dl], 1);
    unsigned short s = (unsigned short)(v & 0xFFFF);
    if (p < SE_CAP) sE[p] = s;
    else eSrc[base + p] = s;
  }
  __syncthreads();
  int lim = cnt < SE_CAP ? cnt : SE_CAP;
  for (int i = t; i < lim; i += 256) eSrc[base+i] = sE[i];
}

// ---------- prep: gstart | W-prepack | emb->fp16 | per-edge (feat,dinv) ----------
__global__ __launch_bounds__(256) void k_prep(const int* __restrict__ batch, int* __restrict__ gStart,
                       const float* __restrict__ W1, const float* __restrict__ W2,
                       const float* __restrict__ W3, short* __restrict__ Bp,
                       const float* __restrict__ emb, __half* __restrict__ embh,
                       const unsigned short* __restrict__ eSrc, const int* __restrict__ feat,
                       const float* __restrict__ dinv,
                       unsigned short* __restrict__ eFeat, float* __restrict__ eDinv){
  int b = blockIdx.x, t = threadIdx.x;
  if (b < NBUCK){                       // gstart
    int i = b*256 + t;
    if (i >= N_NODES) return;
    int bb = batch[i];
    int pb = (i==0) ? -1 : batch[i-1];
    for (int g=pb+1; g<=bb; g++) gStart[g] = i;
    if (i == N_NODES-1)
      for (int g=bb+1; g<=N_GRAPHS; g++) gStart[g] = N_NODES;
  } else if (b < NBUCK+24){             // W prepack (3 layers x 2048 threads)
    int idx = (b-NBUCK)*256 + t;        // 0..6143
    int layer = idx / 2048;
    int r = idx - layer*2048;
    const float* W = (layer==0) ? W1 : (layer==1) ? W2 : W3;
    short* Bh = Bp + (size_t)layer*32768;
    short* Bl = Bh + 16384;
    int lane = r & 63, tile = r >> 6;   // tile = kt*8 + ct
    int kt = tile >> 3, ct = tile & 7;
    int q = lane >> 4, c = ct*16 + (lane & 15);
    #pragma unroll
    for (int i=0;i<8;i++){
      int k = kt*32 + q*8 + i;
      float w = W[k*C + c];
      unsigned short hh = f2bf(w);
      unsigned short ll = f2bf(w - bf2f(hh));
      Bh[(size_t)(tile*64 + lane)*8 + i] = (short)hh;
      Bl[(size_t)(tile*64 + lane)*8 + i] = (short)ll;
    }
  } else if (b < NBUCK+24+64){          // emb -> fp16
    int idx = (b-NBUCK-24)*256 + t;
    const float2* s = (const float2*)emb;
    __half2* d2 = (__half2*)embh;
    for (int i = idx; i < VOCAB*C/2; i += 64*256)
      d2[i] = __float22half2_rn(s[i]);
  } else {                              // per-edge metadata (200 blocks)
    int idx = (b-NBUCK-24-64)*256 + t;
    for (int e = idx; e < N_EDGES; e += 200*256){
      int s = eSrc[e];
      eFeat[e] = (unsigned short)feat[s];
      eDinv[e] = dinv[s];
    }
  }
}

// split-bf16 store of the agg result (u represented to 2^-17 rel)
__device__ __forceinline__ void store_split(unsigned short* uh, unsigned short* ul,
                                            size_t node, int lane, float ax, float ay){
  unsigned short hx = f2bf(ax), hy = f2bf(ay);
  unsigned short lx = f2bf(ax - bf2f(hx)), ly = f2bf(ay - bf2f(hy));
  *(ushort2*)&uh[node*C + 2*lane] = make_ushort2(hx, hy);
  *(ushort2*)&ul[node*C + 2*lane] = make_ushort2(lx, ly);
}

// ---------- agg layer 1 (embedding space, L2-resident table), MLP=8 ----------

__global__ __launch_bounds__(256) void k_agg1(const __half* __restrict__ embh,
                      const unsigned short* __restrict__ eFeat, const float* __restrict__ eDinv,
                      const int* __restrict__ rowStart, const int* __restrict__ deg,
                      const float* __restrict__ dinv, const int* __restrict__ feat,
                      unsigned short* __restrict__ uh, unsigned short* __restrict__ ul){
  int node = blockIdx.x*4 + (threadIdx.x>>6);
  int lane = threadIdx.x & 63;
  if (node >= N_NODES) return;
  int rs = rowStart[node], len = deg[node];
  float dn = dinv[node];
  const __half2* E = (const __half2*)embh;   // row stride 64 half2
  float2 sv = __half22float2(E[(size_t)feat[node]*64 + lane]);
  float2 a = make_float2(dn*sv.x, dn*sv.y);
  int k = 0;
  for (; k+8<=len; k+=8){
    int f[8]; float dd[8];
    #pragma unroll
    for (int j=0;j<8;j++){ f[j] = eFeat[rs+k+j]; dd[j] = eDinv[rs+k+j]; }
    float2 v[8];
    #pragma unroll
    for (int j=0;j<8;j++) v[j] = __half22float2(E[(size_t)f[j]*64 + lane]);
    #pragma unroll
    for (int j=0;j<8;j++){ a.x = fmaf(dd[j], v[j].x, a.x); a.y = fmaf(dd[j], v[j].y, a.y); }
  }
  for (; k<len; k++){
    float dd = eDinv[rs+k];
    float2 v = __half22float2(E[(size_t)eFeat[rs+k]*64 + lane]);
    a.x = fmaf(dd, v.x, a.x); a.y = fmaf(dd, v.y, a.y);
  }
  store_split(uh, ul, (size_t)node, lane, dn*a.x, dn*a.y);
}

// ---------- agg layers 2-3 (xs space), MLP=8 ----------

__global__ __launch_bounds__(256) void k_aggS(const __half* __restrict__ xs, const unsigned short* __restrict__ eSrc,
                      const int* __restrict__ rowStart, const int* __restrict__ deg,
                      const float* __restrict__ dinv,
                      unsigned short* __restrict__ uh, unsigned short* __restrict__ ul){
  int node = blockIdx.x*4 + (threadIdx.x>>6);
  int lane = threadIdx.x & 63;
  if (node >= N_NODES) return;
  int rs = rowStart[node], len = deg[node];
  const __half2* zb = (const __half2*)xs;
  float2 a = __half22float2(zb[(size_t)node*64 + lane]);
  int k = 0;
  for (; k+8<=len; k+=8){
    int s[8];
    #pragma unroll
    for (int j=0;j<8;j++) s[j] = eSrc[rs+k+j];
    float2 v[8];
    #pragma unroll
    for (int j=0;j<8;j++) v[j] = __half22float2(zb[(size_t)s[j]*64 + lane]);
    #pragma unroll
    for (int j=0;j<8;j++){ a.x += v[j].x; a.y += v[j].y; }
  }
  for (; k+4<=len; k+=4){
    int s0=eSrc[rs+k], s1=eSrc[rs+k+1], s2=eSrc[rs+k+2], s3=eSrc[rs+k+3];
    float2 v0=__half22float2(zb[(size_t)s0*64+lane]);
    float2 v1=__half22float2(zb[(size_t)s1*64+lane]);
    float2 v2=__half22float2(zb[(size_t)s2*64+lane]);
    float2 v3=__half22float2(zb[(size_t)s3*64+lane]);
    a.x += v0.x+v1.x+v2.x+v3.x;
    a.y += v0.y+v1.y+v2.y+v3.y;
  }
  for (; k<len; k++){
    float2 v = __half22float2(zb[(size_t)eSrc[rs+k]*64 + lane]);
    a.x += v.x; a.y += v.y;
  }
  float dn = dinv[node];
  store_split(uh, ul, (size_t)node, lane, dn*a.x, dn*a.y);
}

// ---------- gemm layers 1-2: xs = fp16( dinv * relu(u@W + b) ) ----------
// A-frags loaded directly from split-bf16 planes: ZERO conversion VALU.
// 1 row-tile per wave (782 blocks -> better CU balance).

__global__ __launch_bounds__(256) void k_gemmA(
            const unsigned short* __restrict__ uh, const unsigned short* __restrict__ ul,
            const short* __restrict__ Bh, const short* __restrict__ Bl,
            const float* __restrict__ bias, const float* __restrict__ dinv,
            __half* __restrict__ xs){
  int lane = threadIdx.x & 63;
  int pb = blockIdx.x*4 + (threadIdx.x >> 6);
  int R0 = pb*16;
  if (R0 >= N_NODES) return;
  int r15 = lane & 15, q = lane >> 4;
  int row = R0 + r15;
  const short8v* AH = (const short8v*)(uh + (size_t)row*C);
  const short8v* AL = (const short8v*)(ul + (size_t)row*C);
  const short8v* BH = (const short8v*)Bh;
  const short8v* BL = (const short8v*)Bl;
  f32x4 acc[8];
  #pragma unroll
  for (int ct=0;ct<8;ct++) acc[ct] = (f32x4){0.f,0.f,0.f,0.f};
  #pragma unroll
  for (int kt=0; kt<4; kt++){
    short8v ah = AH[kt*4 + q];
    short8v al = AL[kt*4 + q];
    #pragma unroll
    for (int ct=0; ct<8; ct++){
      short8v bh = BH[(kt*8+ct)*64 + lane];
      short8v bl = BL[(kt*8+ct)*64 + lane];
      acc[ct] = __builtin_amdgcn_mfma_f32_16x16x32_bf16(ah, bh, acc[ct], 0, 0, 0);
      acc[ct] = __builtin_amdgcn_mfma_f32_16x16x32_bf16(al, bh, acc[ct], 0, 0, 0);
      acc[ct] = __builtin_amdgcn_mfma_f32_16x16x32_bf16(ah, bl, acc[ct], 0, 0, 0);
    }
  }
  float bb[8];
  #pragma unroll
  for (int ct=0;ct<8;ct++) bb[ct] = bias[ct*16 + r15];
  #pragma unroll
  for (int j=0;j<4;j++){
    int rz = R0 + q*4 + j;
    float d = dinv[rz];
    #pragma unroll
    for (int ct=0; ct<8; ct++){
      float v = fmaxf(acc[ct][j] + bb[ct], 0.f);
      xs[(size_t)rz*C + ct*16 + r15] = __float2half(v * d);
    }
  }
}

// ---------- gemm layer 3: dots[i] = relu(u@W3 + b3) . fcW ----------

__global__ __launch_bounds__(256) void k_gemm3(
            const unsigned short* __restrict__ uh, const unsigned short* __restrict__ ul,
            const short* __restrict__ Bh, const short* __restrict__ Bl,
            const float* __restrict__ bias, const float* __restrict__ fcW,
            float* __restrict__ dots){
  int lane = threadIdx.x & 63;
  int pb = blockIdx.x*4 + (threadIdx.x >> 6);
  int R0 = pb*16;
  if (R0 >= N_NODES) return;
  int r15 = lane & 15, q = lane >> 4;
  int row = R0 + r15;
  const short8v* AH = (const short8v*)(uh + (size_t)row*C);
  const short8v* AL = (const short8v*)(ul + (size_t)row*C);
  const short8v* BH = (const short8v*)Bh;
  const short8v* BL = (const short8v*)Bl;
  f32x4 acc[8];
  #pragma unroll
  for (int ct=0;ct<8;ct++) acc[ct] = (f32x4){0.f,0.f,0.f,0.f};
  #pragma unroll
  for (int kt=0; kt<4; kt++){
    short8v ah = AH[kt*4 + q];
    short8v al = AL[kt*4 + q];
    #pragma unroll
    for (int ct=0; ct<8; ct++){
      short8v bh = BH[(kt*8+ct)*64 + lane];
      short8v bl = BL[(kt*8+ct)*64 + lane];
      acc[ct] = __builtin_amdgcn_mfma_f32_16x16x32_bf16(ah, bh, acc[ct], 0, 0, 0);
      acc[ct] = __builtin_amdgcn_mfma_f32_16x16x32_bf16(al, bh, acc[ct], 0, 0, 0);
      acc[ct] = __builtin_amdgcn_mfma_f32_16x16x32_bf16(ah, bl, acc[ct], 0, 0, 0);
    }
  }
  float bb[8], fw[8];
  #pragma unroll
  for (int ct=0;ct<8;ct++){ bb[ct] = bias[ct*16 + r15]; fw[ct] = fcW[ct*16 + r15]; }
  #pragma unroll
  for (int j=0;j<4;j++){
    int rz = R0 + q*4 + j;
    float s = 0.f;
    #pragma unroll
    for (int ct=0; ct<8; ct++)
      s += fmaxf(acc[ct][j] + bb[ct], 0.f) * fw[ct];
    s += __shfl_xor(s, 1);
    s += __shfl_xor(s, 2);
    s += __shfl_xor(s, 4);
    s += __shfl_xor(s, 8);
    if (r15 == 0) dots[rz] = s;
  }
}

// ---------- pooling ----------

__global__ void k_pool_seg(const float* __restrict__ dots, const int* __restrict__ gStart,
                           const float* __restrict__ fcb, float* __restrict__ out){
  __shared__ float s[256];
  int g = blockIdx.x;
  int st = gStart[g], en = gStart[g+1];
  float acc = 0.f;
  for (int i = st + threadIdx.x; i < en; i += 256) acc += dots[i];
  s[threadIdx.x] = acc; __syncthreads();
  for (int off=128; off>0; off>>=1){
    if (threadIdx.x < off) s[threadIdx.x] += s[threadIdx.x+off];
    __syncthreads();
  }
  if (threadIdx.x==0) out[g] = s[0]/fmaxf((float)(en-st),1.0f) + fcb[0];
}

// ---------- launch ----------

extern "C" void kernel_launch(void* const* d_in, const int* in_sizes, int n_in,
                              void* d_out, int out_size, void* d_ws, size_t ws_size,
                              hipStream_t stream){
  const int* edge  = (const int*)d_in[0];
  const int* srcI  = edge;
  const int* dstI  = edge + N_EDGES;
  const int* feat  = (const int*)d_in[1];
  const int* batch = (const int*)d_in[2];
  const float* emb = (const float*)d_in[3];
  const float* W1  = (const float*)d_in[4];
  const float* b1  = (const float*)d_in[5];
  const float* W2  = (const float*)d_in[6];
  const float* b2  = (const float*)d_in[7];
  const float* W3  = (const float*)d_in[8];
  const float* b3  = (const float*)d_in[9];
  const float* fcW = (const float*)d_in[10];
  const float* fcb = (const float*)d_in[11];
  float* out = (float*)d_out;

  __half* xs = (__half*)d_ws;                        // N*C f16 (gather target)
  unsigned short* uhp = (unsigned short*)(xs + (size_t)N_NODES*C);  // N*C u16
  unsigned short* ulp = uhp + (size_t)N_NODES*C;     // N*C u16
  __half* embh = (__half*)(ulp + (size_t)N_NODES*C); // VOCAB*C f16
  unsigned* binned = (unsigned*)(embh + (size_t)VOCAB*C); // 800000 u32
  unsigned short* eSrc  = (unsigned short*)(binned + N_EDGES);  // 800000 u16
  unsigned short* eFeat = eSrc + N_EDGES;            // 800000 u16
  float* eDinv  = (float*)(eFeat + N_EDGES);         // 800000 f32
  int* rowStart = (int*)(eDinv + N_EDGES);           // 50000
  int* deg      = rowStart + N_NODES;                // 50000
  float* dinv   = (float*)(deg + N_NODES);           // 50000
  int* blockHist = (int*)(dinv + N_NODES);           // 256*200
  int* blockOfs  = blockHist + 256*A_BLOCKS;         // 256*200
  int* bucketTot = blockOfs + 256*A_BLOCKS;          // 256
  int* bucketBase = bucketTot + 256;                 // 257 (+pad)
  int* gStart     = bucketBase + 260;                // 513 (+pad)
  float* dots   = (float*)(gStart + 520);            // 50000
  short* Bpack  = (short*)(dots + N_NODES);          // 6*16384 shorts
  short* Bh1 = Bpack,           * Bl1 = Bpack + 16384;
  short* Bh2 = Bpack + 2*16384, * Bl2 = Bpack + 3*16384;
  short* Bh3 = Bpack + 4*16384, * Bl3 = Bpack + 5*16384;

  k_binCount  <<<A_BLOCKS, 256, 0, stream>>>(dstI, blockHist);
  k_binScanA  <<<256, 64, 0, stream>>>(blockHist, blockOfs, bucketTot);
  k_binScanB  <<<1, 256, 0, stream>>>(bucketTot, bucketBase);
  k_binScatter<<<A_BLOCKS, 256, 0, stream>>>(srcI, dstI, bucketBase, blockOfs, binned);
  k_binFinal  <<<NBUCK, 256, 0, stream>>>(binned, bucketBase, eSrc, rowStart, deg, dinv);
  k_prep      <<<NBUCK+24+64+200, 256, 0, stream>>>(batch, gStart, W1, W2, W3, Bpack,
                                                    emb, embh, eSrc, feat, dinv, eFeat, eDinv);

  int aggBlocks  = (N_NODES+3)/4;        // 12500
  int gemmBlocks = (N_NODES/16 + 3)/4;   // 782 (1 row-tile per wave)
  // layer 1: aggregate in embedding space, then GEMM
  k_agg1 <<<aggBlocks, 256, 0, stream>>>(embh, eFeat, eDinv, rowStart, deg, dinv, feat, uhp, ulp);
  k_gemmA<<<gemmBlocks, 256, 0, stream>>>(uhp, ulp, Bh1, Bl1, b1, dinv, xs);
  // layer 2
  k_aggS <<<aggBlocks, 256, 0, stream>>>(xs, eSrc, rowStart, deg, dinv, uhp, ulp);
  k_gemmA<<<gemmBlocks, 256, 0, stream>>>(uhp, ulp, Bh2, Bl2, b2, dinv, xs);
  // layer 3: gemm emits per-node dot with fcW directly
  k_aggS <<<aggBlocks, 256, 0, stream>>>(xs, eSrc, rowStart, deg, dinv, uhp, ulp);
  k_gemm3<<<gemmBlocks, 256, 0, stream>>>(uhp, ulp, Bh3, Bl3, b3, fcW, dots);

  k_pool_seg<<<N_GRAPHS, 256, 0, stream>>>(dots, gStart, fcb, out);
}

// Round 11
// 198.041 us; speedup vs baseline: 1.4130x; 1.0396x over previous
//
#include <hip/hip_runtime.h>
#include <hip/hip_fp16.h>

#define N_NODES 50000
#define N_EDGES 800000
#define N_GRAPHS 512
#define VOCAB 10000
#define C 128
#define NBUCK 196            // ceil(50000/256), bucket = dst>>8
#define A_BLOCKS 200         // 4000 edges each
#define EDGES_PER_A (N_EDGES / A_BLOCKS)
#define SE_CAP 8192          // LDS eSrc staging per bucket (mean 4096)

typedef __attribute__((ext_vector_type(8))) short short8v;
typedef __attribute__((ext_vector_type(4))) float f32x4;

__device__ __forceinline__ unsigned short f2bf(float f){
  unsigned u = __builtin_bit_cast(unsigned, f);
  unsigned r = u + 0x7FFFu + ((u >> 16) & 1u);
  return (unsigned short)(r >> 16);
}
__device__ __forceinline__ float bf2f(unsigned short h){
  unsigned u = ((unsigned)h) << 16;
  return __builtin_bit_cast(float, u);
}
__device__ __forceinline__ float h2f(short s){
  return __half2float(__builtin_bit_cast(__half, (unsigned short)s));
}

// ---------- binning A1: per-block bucket histograms (bucket-major store) ----------
__global__ __launch_bounds__(256) void k_binCount(const int* __restrict__ dst, int* __restrict__ blockHist){
  __shared__ int h[256];
  int t = threadIdx.x;
  h[t] = 0; __syncthreads();
  int base = blockIdx.x * EDGES_PER_A;
  for (int i = t; i < EDGES_PER_A; i += 256)
    atomicAdd(&h[dst[base+i] >> 8], 1);
  __syncthreads();
  blockHist[t*A_BLOCKS + blockIdx.x] = h[t];   // bucket-major
}

// ---------- scan A: wave per bucket, prefix over 200 block entries ----------
__global__ __launch_bounds__(64) void k_binScanA(const int* __restrict__ blockHist,
                        int* __restrict__ blockOfs, int* __restrict__ bucketTot){
  int b = blockIdx.x;        // bucket (0..255)
  int l = threadIdx.x;       // lane
  int carry = 0;
  for (int c = 0; c < 256; c += 64){
    int idx = c + l;
    int v = (idx < A_BLOCKS) ? blockHist[b*A_BLOCKS + idx] : 0;
    int x = v;
    #pragma unroll
    for (int off=1; off<64; off<<=1){
      int y = __shfl_up(x, off);
      if (l >= off) x += y;
    }
    if (idx < A_BLOCKS) blockOfs[b*A_BLOCKS + idx] = carry + x - v;  // exclusive
    carry += __shfl(x, 63);
  }
  if (l == 0) bucketTot[b] = carry;
}

// ---------- scan B: exclusive scan of 256 bucket totals ----------
__global__ void k_binScanB(const int* __restrict__ bucketTot, int* __restrict__ bucketBase){
  __shared__ int s[256];
  int t = threadIdx.x;
  int v = bucketTot[t];
  s[t] = v; __syncthreads();
  for (int off=1; off<256; off<<=1){
    int u = (t>=off) ? s[t-off] : 0;
    __syncthreads();
    s[t] += u;
    __syncthreads();
  }
  bucketBase[t+1] = s[t];
  if (t == 0) bucketBase[0] = 0;
}

// ---------- binning A2: scatter packed edges (no global atomics) ----------
__global__ __launch_bounds__(256) void k_binScatter(const int* __restrict__ src, const int* __restrict__ dst,
                           const int* __restrict__ bucketBase, const int* __restrict__ blockOfs,
                           unsigned* __restrict__ binned){
  __shared__ int ofs[256], cur[256];
  int t = threadIdx.x;
  ofs[t] = bucketBase[t] + blockOfs[t*A_BLOCKS + blockIdx.x];
  cur[t] = 0;
  __syncthreads();
  int base = blockIdx.x * EDGES_PER_A;
  for (int i = t; i < EDGES_PER_A; i += 256){
    int d = dst[base+i];
    int b = d >> 8;
    int p = atomicAdd(&cur[b], 1);
    binned[ofs[b] + p] = (unsigned)(src[base+i] & 0xFFFF) | ((unsigned)(d & 0xFF) << 16);
  }
}

// ---------- binning B: per-bucket CSR finalize ----------
__global__ __launch_bounds__(256) void k_binFinal(const unsigned* __restrict__ binned,
                         const int* __restrict__ bucketBase,
                         unsigned short* __restrict__ eSrc, int* __restrict__ rowStart,
                         int* __restrict__ deg, float* __restrict__ dinv){
  __shared__ int h[256], pre[256], cur[256];
  __shared__ unsigned short sE[SE_CAP];
  int b = blockIdx.x;
  int t = threadIdx.x;
  int base = bucketBase[b], cnt = bucketBase[b+1] - base;
  int nodeBase = b << 8;
  h[t] = 0; __syncthreads();
  for (int i = t; i < cnt; i += 256)
    atomicAdd(&h[binned[base+i] >> 16], 1);
  __syncthreads();
  pre[t] = h[t]; __syncthreads();
  for (int off=1; off<256; off<<=1){
    int u = (t>=off) ? pre[t-off] : 0;
    __syncthreads();
    pre[t] += u;
    __syncthreads();
  }
  int node = nodeBase + t;
  if (node < N_NODES){
    int d = h[t];
    deg[node] = d;
    rowStart[node] = base + pre[t] - d;
    dinv[node] = rsqrtf((float)d + 1.0f);
  }
  cur[t] = pre[t] - h[t];
  __syncthreads();
  for (int i = t; i < cnt; i += 256){
    unsigned v = binned[base+i];
    int dl = v >> 16;
    int p = atomicAdd(&cur[dl], 1);
    unsigned short s = (unsigned short)(v & 0xFFFF);
    if (p < SE_CAP) sE[p] = s;
    else eSrc[base + p] = s;
  }
  __syncthreads();
  int lim = cnt < SE_CAP ? cnt : SE_CAP;
  for (int i = t; i < lim; i += 256) eSrc[base+i] = sE[i];
}

// ---------- prep: gstart | W-prepack | emb->fp16 | per-edge (feat,dinv) ----------
__global__ __launch_bounds__(256) void k_prep(const int* __restrict__ batch, int* __restrict__ gStart,
                       const float* __restrict__ W1, const float* __restrict__ W2,
                       const float* __restrict__ W3, short* __restrict__ Bp,
                       const float* __restrict__ emb, __half* __restrict__ embh,
                       const unsigned short* __restrict__ eSrc, const int* __restrict__ feat,
                       const float* __restrict__ dinv,
                       unsigned short* __restrict__ eFeat, float* __restrict__ eDinv){
  int b = blockIdx.x, t = threadIdx.x;
  if (b < NBUCK){                       // gstart
    int i = b*256 + t;
    if (i >= N_NODES) return;
    int bb = batch[i];
    int pb = (i==0) ? -1 : batch[i-1];
    for (int g=pb+1; g<=bb; g++) gStart[g] = i;
    if (i == N_NODES-1)
      for (int g=bb+1; g<=N_GRAPHS; g++) gStart[g] = N_NODES;
  } else if (b < NBUCK+24){             // W prepack (3 layers x 2048 threads)
    int idx = (b-NBUCK)*256 + t;        // 0..6143
    int layer = idx / 2048;
    int r = idx - layer*2048;
    const float* W = (layer==0) ? W1 : (layer==1) ? W2 : W3;
    short* Bh = Bp + (size_t)layer*32768;
    short* Bl = Bh + 16384;
    int lane = r & 63, tile = r >> 6;   // tile = kt*8 + ct
    int kt = tile >> 3, ct = tile & 7;
    int q = lane >> 4, c = ct*16 + (lane & 15);
    #pragma unroll
    for (int i=0;i<8;i++){
      int k = kt*32 + q*8 + i;
      float w = W[k*C + c];
      unsigned short hh = f2bf(w);
      unsigned short ll = f2bf(w - bf2f(hh));
      Bh[(size_t)(tile*64 + lane)*8 + i] = (short)hh;
      Bl[(size_t)(tile*64 + lane)*8 + i] = (short)ll;
    }
  } else if (b < NBUCK+24+64){          // emb -> fp16
    int idx = (b-NBUCK-24)*256 + t;
    const float2* s = (const float2*)emb;
    __half2* d2 = (__half2*)embh;
    for (int i = idx; i < VOCAB*C/2; i += 64*256)
      d2[i] = __float22half2_rn(s[i]);
  } else {                              // per-edge metadata (200 blocks)
    int idx = (b-NBUCK-24-64)*256 + t;
    for (int e = idx; e < N_EDGES; e += 200*256){
      int s = eSrc[e];
      eFeat[e] = (unsigned short)feat[s];
      eDinv[e] = dinv[s];
    }
  }
}

// split-bf16 store of 8 values (16B per plane per lane)
__device__ __forceinline__ void store_split8(unsigned short* uh, unsigned short* ul,
                                             size_t node, int l16, const float* a){
  short8v hv, lv;
  #pragma unroll
  for (int i=0;i<8;i++){
    unsigned short hh = f2bf(a[i]);
    hv[i] = (short)hh;
    lv[i] = (short)f2bf(a[i] - bf2f(hh));
  }
  *(short8v*)&uh[node*C + l16*8] = hv;
  *(short8v*)&ul[node*C + l16*8] = lv;
}

// ---------- agg layer 1: quarter-wave per node (16 lanes x 16B row chunk), MLP=32/wave ----------
// u[i] = split_bf16( dinv_i * ( dinv_i*embh[feat_i] + sum_e eDinv[e]*embh[eFeat[e]] ) )

__global__ __launch_bounds__(256) void k_agg1(const __half* __restrict__ embh,
                      const unsigned short* __restrict__ eFeat, const float* __restrict__ eDinv,
                      const int* __restrict__ rowStart, const int* __restrict__ deg,
                      const float* __restrict__ dinv, const int* __restrict__ feat,
                      unsigned short* __restrict__ uh, unsigned short* __restrict__ ul){
  int t = threadIdx.x;
  int wave = t>>6, lane = t&63;
  int sub = lane>>4, l16 = lane&15;
  int node = blockIdx.x*16 + wave*4 + sub;
  if (node >= N_NODES) return;
  int rs = rowStart[node], len = deg[node];
  float dn = dinv[node];
  const short8v* E = (const short8v*)embh;   // 16 chunks per row
  float a[8];
  {
    short8v v = E[(size_t)feat[node]*16 + l16];
    #pragma unroll
    for (int i=0;i<8;i++) a[i] = dn * h2f(v[i]);
  }
  int k = 0;
  for (; k+8<=len; k+=8){
    int f[8]; float dd[8];
    #pragma unroll
    for (int j=0;j<8;j++){ f[j] = eFeat[rs+k+j]; dd[j] = eDinv[rs+k+j]; }
    short8v v[8];
    #pragma unroll
    for (int j=0;j<8;j++) v[j] = E[(size_t)f[j]*16 + l16];
    #pragma unroll
    for (int j=0;j<8;j++)
      #pragma unroll
      for (int i=0;i<8;i++) a[i] = fmaf(dd[j], h2f(v[j][i]), a[i]);
  }
  for (; k<len; k++){
    float dd = eDinv[rs+k];
    short8v v = E[(size_t)eFeat[rs+k]*16 + l16];
    #pragma unroll
    for (int i=0;i<8;i++) a[i] = fmaf(dd, h2f(v[i]), a[i]);
  }
  #pragma unroll
  for (int i=0;i<8;i++) a[i] *= dn;
  store_split8(uh, ul, (size_t)node, l16, a);
}

// ---------- agg layers 2-3: quarter-wave per node ----------

__global__ __launch_bounds__(256) void k_aggS(const __half* __restrict__ xs, const unsigned short* __restrict__ eSrc,
                      const int* __restrict__ rowStart, const int* __restrict__ deg,
                      const float* __restrict__ dinv,
                      unsigned short* __restrict__ uh, unsigned short* __restrict__ ul){
  int t = threadIdx.x;
  int wave = t>>6, lane = t&63;
  int sub = lane>>4, l16 = lane&15;
  int node = blockIdx.x*16 + wave*4 + sub;
  if (node >= N_NODES) return;
  int rs = rowStart[node], len = deg[node];
  const short8v* X = (const short8v*)xs;   // 16 chunks per row
  float a[8];
  {
    short8v v = X[(size_t)node*16 + l16];
    #pragma unroll
    for (int i=0;i<8;i++) a[i] = h2f(v[i]);
  }
  int k = 0;
  for (; k+8<=len; k+=8){
    int s[8];
    #pragma unroll
    for (int j=0;j<8;j++) s[j] = eSrc[rs+k+j];
    short8v v[8];
    #pragma unroll
    for (int j=0;j<8;j++) v[j] = X[(size_t)s[j]*16 + l16];
    #pragma unroll
    for (int j=0;j<8;j++)
      #pragma unroll
      for (int i=0;i<8;i++) a[i] += h2f(v[j][i]);
  }
  for (; k<len; k++){
    short8v v = X[(size_t)eSrc[rs+k]*16 + l16];
    #pragma unroll
    for (int i=0;i<8;i++) a[i] += h2f(v[i]);
  }
  float dn = dinv[node];
  #pragma unroll
  for (int i=0;i<8;i++) a[i] *= dn;
  store_split8(uh, ul, (size_t)node, l16, a);
}

// ---------- gemm layers 1-2: xs = fp16( dinv * relu(u@W + b) ), zero-conversion MFMA ----------

__global__ __launch_bounds__(256) void k_gemmA(
            const unsigned short* __restrict__ uh, const unsigned short* __restrict__ ul,
            const short* __restrict__ Bh, const short* __restrict__ Bl,
            const float* __restrict__ bias, const float* __restrict__ dinv,
            __half* __restrict__ xs){
  int lane = threadIdx.x & 63;
  int pb = blockIdx.x*4 + (threadIdx.x >> 6);
  int R0 = pb*16;
  if (R0 >= N_NODES) return;
  int r15 = lane & 15, q = lane >> 4;
  int row = R0 + r15;
  const short8v* AH = (const short8v*)(uh + (size_t)row*C);
  const short8v* AL = (const short8v*)(ul + (size_t)row*C);
  const short8v* BH = (const short8v*)Bh;
  const short8v* BL = (const short8v*)Bl;
  f32x4 acc[8];
  #pragma unroll
  for (int ct=0;ct<8;ct++) acc[ct] = (f32x4){0.f,0.f,0.f,0.f};
  #pragma unroll
  for (int kt=0; kt<4; kt++){
    short8v ah = AH[kt*4 + q];
    short8v al = AL[kt*4 + q];
    #pragma unroll
    for (int ct=0; ct<8; ct++){
      short8v bh = BH[(kt*8+ct)*64 + lane];
      short8v bl = BL[(kt*8+ct)*64 + lane];
      acc[ct] = __builtin_amdgcn_mfma_f32_16x16x32_bf16(ah, bh, acc[ct], 0, 0, 0);
      acc[ct] = __builtin_amdgcn_mfma_f32_16x16x32_bf16(al, bh, acc[ct], 0, 0, 0);
      acc[ct] = __builtin_amdgcn_mfma_f32_16x16x32_bf16(ah, bl, acc[ct], 0, 0, 0);
    }
  }
  float bb[8];
  #pragma unroll
  for (int ct=0;ct<8;ct++) bb[ct] = bias[ct*16 + r15];
  #pragma unroll
  for (int j=0;j<4;j++){
    int rz = R0 + q*4 + j;
    float d = dinv[rz];
    #pragma unroll
    for (int ct=0; ct<8; ct++){
      float v = fmaxf(acc[ct][j] + bb[ct], 0.f);
      xs[(size_t)rz*C + ct*16 + r15] = __float2half(v * d);
    }
  }
}

// ---------- gemm layer 3: dots[i] = relu(u@W3 + b3) . fcW ----------

__global__ __launch_bounds__(256) void k_gemm3(
            const unsigned short* __restrict__ uh, const unsigned short* __restrict__ ul,
            const short* __restrict__ Bh, const short* __restrict__ Bl,
            const float* __restrict__ bias, const float* __restrict__ fcW,
            float* __restrict__ dots){
  int lane = threadIdx.x & 63;
  int pb = blockIdx.x*4 + (threadIdx.x >> 6);
  int R0 = pb*16;
  if (R0 >= N_NODES) return;
  int r15 = lane & 15, q = lane >> 4;
  int row = R0 + r15;
  const short8v* AH = (const short8v*)(uh + (size_t)row*C);
  const short8v* AL = (const short8v*)(ul + (size_t)row*C);
  const short8v* BH = (const short8v*)Bh;
  const short8v* BL = (const short8v*)Bl;
  f32x4 acc[8];
  #pragma unroll
  for (int ct=0;ct<8;ct++) acc[ct] = (f32x4){0.f,0.f,0.f,0.f};
  #pragma unroll
  for (int kt=0; kt<4; kt++){
    short8v ah = AH[kt*4 + q];
    short8v al = AL[kt*4 + q];
    #pragma unroll
    for (int ct=0; ct<8; ct++){
      short8v bh = BH[(kt*8+ct)*64 + lane];
      short8v bl = BL[(kt*8+ct)*64 + lane];
      acc[ct] = __builtin_amdgcn_mfma_f32_16x16x32_bf16(ah, bh, acc[ct], 0, 0, 0);
      acc[ct] = __builtin_amdgcn_mfma_f32_16x16x32_bf16(al, bh, acc[ct], 0, 0, 0);
      acc[ct] = __builtin_amdgcn_mfma_f32_16x16x32_bf16(ah, bl, acc[ct], 0, 0, 0);
    }
  }
  float bb[8], fw[8];
  #pragma unroll
  for (int ct=0;ct<8;ct++){ bb[ct] = bias[ct*16 + r15]; fw[ct] = fcW[ct*16 + r15]; }
  #pragma unroll
  for (int j=0;j<4;j++){
    int rz = R0 + q*4 + j;
    float s = 0.f;
    #pragma unroll
    for (int ct=0; ct<8; ct++)
      s += fmaxf(acc[ct][j] + bb[ct], 0.f) * fw[ct];
    s += __shfl_xor(s, 1);
    s += __shfl_xor(s, 2);
    s += __shfl_xor(s, 4);
    s += __shfl_xor(s, 8);
    if (r15 == 0) dots[rz] = s;
  }
}

// ---------- pooling ----------

__global__ void k_pool_seg(const float* __restrict__ dots, const int* __restrict__ gStart,
                           const float* __restrict__ fcb, float* __restrict__ out){
  __shared__ float s[256];
  int g = blockIdx.x;
  int st = gStart[g], en = gStart[g+1];
  float acc = 0.f;
  for (int i = st + threadIdx.x; i < en; i += 256) acc += dots[i];
  s[threadIdx.x] = acc; __syncthreads();
  for (int off=128; off>0; off>>=1){
    if (threadIdx.x < off) s[threadIdx.x] += s[threadIdx.x+off];
    __syncthreads();
  }
  if (threadIdx.x==0) out[g] = s[0]/fmaxf((float)(en-st),1.0f) + fcb[0];
}

// ---------- launch ----------

extern "C" void kernel_launch(void* const* d_in, const int* in_sizes, int n_in,
                              void* d_out, int out_size, void* d_ws, size_t ws_size,
                              hipStream_t stream){
  const int* edge  = (const int*)d_in[0];
  const int* srcI  = edge;
  const int* dstI  = edge + N_EDGES;
  const int* feat  = (const int*)d_in[1];
  const int* batch = (const int*)d_in[2];
  const float* emb = (const float*)d_in[3];
  const float* W1  = (const float*)d_in[4];
  const float* b1  = (const float*)d_in[5];
  const float* W2  = (const float*)d_in[6];
  const float* b2  = (const float*)d_in[7];
  const float* W3  = (const float*)d_in[8];
  const float* b3  = (const float*)d_in[9];
  const float* fcW = (const float*)d_in[10];
  const float* fcb = (const float*)d_in[11];
  float* out = (float*)d_out;

  __half* xs = (__half*)d_ws;                        // N*C f16 (gather target)
  unsigned short* uhp = (unsigned short*)(xs + (size_t)N_NODES*C);  // N*C u16
  unsigned short* ulp = uhp + (size_t)N_NODES*C;     // N*C u16
  __half* embh = (__half*)(ulp + (size_t)N_NODES*C); // VOCAB*C f16
  unsigned* binned = (unsigned*)(embh + (size_t)VOCAB*C); // 800000 u32
  unsigned short* eSrc  = (unsigned short*)(binned + N_EDGES);  // 800000 u16
  unsigned short* eFeat = eSrc + N_EDGES;            // 800000 u16
  float* eDinv  = (float*)(eFeat + N_EDGES);         // 800000 f32
  int* rowStart = (int*)(eDinv + N_EDGES);           // 50000
  int* deg      = rowStart + N_NODES;                // 50000
  float* dinv   = (float*)(deg + N_NODES);           // 50000
  int* blockHist = (int*)(dinv + N_NODES);           // 256*200
  int* blockOfs  = blockHist + 256*A_BLOCKS;         // 256*200
  int* bucketTot = blockOfs + 256*A_BLOCKS;          // 256
  int* bucketBase = bucketTot + 256;                 // 257 (+pad)
  int* gStart     = bucketBase + 260;                // 513 (+pad)
  float* dots   = (float*)(gStart + 520);            // 50000
  short* Bpack  = (short*)(dots + N_NODES);          // 6*16384 shorts
  short* Bh1 = Bpack,           * Bl1 = Bpack + 16384;
  short* Bh2 = Bpack + 2*16384, * Bl2 = Bpack + 3*16384;
  short* Bh3 = Bpack + 4*16384, * Bl3 = Bpack + 5*16384;

  k_binCount  <<<A_BLOCKS, 256, 0, stream>>>(dstI, blockHist);
  k_binScanA  <<<256, 64, 0, stream>>>(blockHist, blockOfs, bucketTot);
  k_binScanB  <<<1, 256, 0, stream>>>(bucketTot, bucketBase);
  k_binScatter<<<A_BLOCKS, 256, 0, stream>>>(srcI, dstI, bucketBase, blockOfs, binned);
  k_binFinal  <<<NBUCK, 256, 0, stream>>>(binned, bucketBase, eSrc, rowStart, deg, dinv);
  k_prep      <<<NBUCK+24+64+200, 256, 0, stream>>>(batch, gStart, W1, W2, W3, Bpack,
                                                    emb, embh, eSrc, feat, dinv, eFeat, eDinv);

  int aggBlocks  = (N_NODES+15)/16;      // 3125 (16 nodes per block, 4 per wave)
  int gemmBlocks = (N_NODES/16 + 3)/4;   // 782 (1 row-tile per wave)
  // layer 1: aggregate in embedding space, then GEMM
  k_agg1 <<<aggBlocks, 256, 0, stream>>>(embh, eFeat, eDinv, rowStart, deg, dinv, feat, uhp, ulp);
  k_gemmA<<<gemmBlocks, 256, 0, stream>>>(uhp, ulp, Bh1, Bl1, b1, dinv, xs);
  // layer 2
  k_aggS <<<aggBlocks, 256, 0, stream>>>(xs, eSrc, rowStart, deg, dinv, uhp, ulp);
  k_gemmA<<<gemmBlocks, 256, 0, stream>>>(uhp, ulp, Bh2, Bl2, b2, dinv, xs);
  // layer 3: gemm emits per-node dot with fcW directly
  k_aggS <<<aggBlocks, 256, 0, stream>>>(xs, eSrc, rowStart, deg, dinv, uhp, ulp);
  k_gemm3<<<gemmBlocks, 256, 0, stream>>>(uhp, ulp, Bh3, Bl3, b3, fcW, dots);

  k_pool_seg<<<N_GRAPHS, 256, 0, stream>>>(dots, gStart, fcb, out);
}

// Round 12
// 193.379 us; speedup vs baseline: 1.4471x; 1.0241x over previous
//
#include <hip/hip_runtime.h>
#include <hip/hip_fp16.h>

#define N_NODES 50000
#define N_EDGES 800000
#define N_GRAPHS 512
#define VOCAB 10000
#define C 128
#define NBUCK 196            // ceil(50000/256), bucket = dst>>8
#define A_BLOCKS 200         // 4000 edges each
#define EDGES_PER_A (N_EDGES / A_BLOCKS)
#define SE_CAP 8192          // LDS eSrc staging per bucket (mean 4096)

typedef __attribute__((ext_vector_type(8))) short short8v;
typedef __attribute__((ext_vector_type(4))) float f32x4;

__device__ __forceinline__ unsigned short f2bf(float f){
  unsigned u = __builtin_bit_cast(unsigned, f);
  unsigned r = u + 0x7FFFu + ((u >> 16) & 1u);
  return (unsigned short)(r >> 16);
}
__device__ __forceinline__ float bf2f(unsigned short h){
  unsigned u = ((unsigned)h) << 16;
  return __builtin_bit_cast(float, u);
}
__device__ __forceinline__ float h2f(short s){
  return __half2float(__builtin_bit_cast(__half, (unsigned short)s));
}

// ---------- K1: binCount (200) | gstart (196) | W-prepack (24) | emb->fp16 (64) ----------
__global__ __launch_bounds__(256) void k_pre(const int* __restrict__ dst, int* __restrict__ blockHist,
                      const int* __restrict__ batch, int* __restrict__ gStart,
                      const float* __restrict__ W1, const float* __restrict__ W2,
                      const float* __restrict__ W3, short* __restrict__ Bp,
                      const float* __restrict__ emb, __half* __restrict__ embh){
  __shared__ int h[256];
  int b = blockIdx.x, t = threadIdx.x;
  if (b < A_BLOCKS){                    // binCount (bucket-major store)
    h[t] = 0; __syncthreads();
    int base = b * EDGES_PER_A;
    for (int i = t; i < EDGES_PER_A; i += 256)
      atomicAdd(&h[dst[base+i] >> 8], 1);
    __syncthreads();
    blockHist[t*A_BLOCKS + b] = h[t];
  } else if (b < A_BLOCKS+NBUCK){       // gstart
    int i = (b-A_BLOCKS)*256 + t;
    if (i >= N_NODES) return;
    int bb = batch[i];
    int pb = (i==0) ? -1 : batch[i-1];
    for (int g=pb+1; g<=bb; g++) gStart[g] = i;
    if (i == N_NODES-1)
      for (int g=bb+1; g<=N_GRAPHS; g++) gStart[g] = N_NODES;
  } else if (b < A_BLOCKS+NBUCK+24){    // W prepack (3 layers x 2048 threads)
    int idx = (b-A_BLOCKS-NBUCK)*256 + t;  // 0..6143
    int layer = idx / 2048;
    int r = idx - layer*2048;
    const float* W = (layer==0) ? W1 : (layer==1) ? W2 : W3;
    short* Bh = Bp + (size_t)layer*32768;
    short* Bl = Bh + 16384;
    int lane = r & 63, tile = r >> 6;   // tile = kt*8 + ct
    int kt = tile >> 3, ct = tile & 7;
    int q = lane >> 4, c = ct*16 + (lane & 15);
    #pragma unroll
    for (int i=0;i<8;i++){
      int k = kt*32 + q*8 + i;
      float w = W[k*C + c];
      unsigned short hh = f2bf(w);
      unsigned short ll = f2bf(w - bf2f(hh));
      Bh[(size_t)(tile*64 + lane)*8 + i] = (short)hh;
      Bl[(size_t)(tile*64 + lane)*8 + i] = (short)ll;
    }
  } else {                              // emb -> fp16 (64 blocks)
    int idx = (b-A_BLOCKS-NBUCK-24)*256 + t;
    const float2* s = (const float2*)emb;
    __half2* d2 = (__half2*)embh;
    for (int i = idx; i < VOCAB*C/2; i += 64*256)
      d2[i] = __float22half2_rn(s[i]);
  }
}

// ---------- scan A: wave per bucket, prefix over 200 block entries ----------
__global__ __launch_bounds__(64) void k_binScanA(const int* __restrict__ blockHist,
                        int* __restrict__ blockOfs, int* __restrict__ bucketTot){
  int b = blockIdx.x;        // bucket (0..255)
  int l = threadIdx.x;       // lane
  int carry = 0;
  for (int c = 0; c < 256; c += 64){
    int idx = c + l;
    int v = (idx < A_BLOCKS) ? blockHist[b*A_BLOCKS + idx] : 0;
    int x = v;
    #pragma unroll
    for (int off=1; off<64; off<<=1){
      int y = __shfl_up(x, off);
      if (l >= off) x += y;
    }
    if (idx < A_BLOCKS) blockOfs[b*A_BLOCKS + idx] = carry + x - v;  // exclusive
    carry += __shfl(x, 63);
  }
  if (l == 0) bucketTot[b] = carry;
}

// ---------- binning A2: scatter packed edges (bucket bases scanned in-block) ----------
__global__ __launch_bounds__(256) void k_binScatter(const int* __restrict__ src, const int* __restrict__ dst,
                           const int* __restrict__ bucketTot, const int* __restrict__ blockOfs,
                           unsigned* __restrict__ binned){
  __shared__ int s[256], ofs[256], cur[256];
  int t = threadIdx.x;
  int tv = bucketTot[t];
  s[t] = tv; __syncthreads();
  for (int off=1; off<256; off<<=1){
    int u = (t>=off) ? s[t-off] : 0;
    __syncthreads();
    s[t] += u;
    __syncthreads();
  }
  ofs[t] = (s[t] - tv) + blockOfs[t*A_BLOCKS + blockIdx.x];
  cur[t] = 0;
  __syncthreads();
  int base = blockIdx.x * EDGES_PER_A;
  for (int i = t; i < EDGES_PER_A; i += 256){
    int d = dst[base+i];
    int b = d >> 8;
    int p = atomicAdd(&cur[b], 1);
    binned[ofs[b] + p] = (unsigned)(src[base+i] & 0xFFFF) | ((unsigned)(d & 0xFF) << 16);
  }
}

// ---------- binning B: per-bucket CSR finalize + eFeat epilogue ----------
__global__ __launch_bounds__(256) void k_binFinal(const unsigned* __restrict__ binned,
                         const int* __restrict__ bucketTot, const int* __restrict__ feat,
                         unsigned short* __restrict__ eSrc, unsigned short* __restrict__ eFeat,
                         int* __restrict__ rowStart, int* __restrict__ deg, float* __restrict__ dinv){
  __shared__ int h[256], pre[256], cur[256], excl[256];
  __shared__ unsigned short sE[SE_CAP];
  int b = blockIdx.x;
  int t = threadIdx.x;
  // in-block exclusive scan of bucketTot -> base for bucket b
  int tv = bucketTot[t];
  pre[t] = tv; __syncthreads();
  for (int off=1; off<256; off<<=1){
    int u = (t>=off) ? pre[t-off] : 0;
    __syncthreads();
    pre[t] += u;
    __syncthreads();
  }
  excl[t] = pre[t] - tv;
  __syncthreads();
  int base = excl[b], cnt = bucketTot[b];
  int nodeBase = b << 8;
  h[t] = 0; __syncthreads();
  for (int i = t; i < cnt; i += 256)
    atomicAdd(&h[binned[base+i] >> 16], 1);
  __syncthreads();
  pre[t] = h[t]; __syncthreads();
  for (int off=1; off<256; off<<=1){
    int u = (t>=off) ? pre[t-off] : 0;
    __syncthreads();
    pre[t] += u;
    __syncthreads();
  }
  int node = nodeBase + t;
  if (node < N_NODES){
    int d = h[t];
    deg[node] = d;
    rowStart[node] = base + pre[t] - d;
    dinv[node] = rsqrtf((float)d + 1.0f);
  }
  cur[t] = pre[t] - h[t];
  __syncthreads();
  for (int i = t; i < cnt; i += 256){
    unsigned v = binned[base+i];
    int dl = v >> 16;
    int p = atomicAdd(&cur[dl], 1);
    unsigned short s = (unsigned short)(v & 0xFFFF);
    if (p < SE_CAP) sE[p] = s;
    else eSrc[base + p] = s;
  }
  __syncthreads();
  int lim = cnt < SE_CAP ? cnt : SE_CAP;
  for (int i = t; i < lim; i += 256){
    unsigned short sv = sE[i];
    eSrc[base+i]  = sv;
    eFeat[base+i] = (unsigned short)feat[sv];
  }
  for (int i = SE_CAP + t; i < cnt; i += 256){   // overflow fallback path
    eFeat[base+i] = (unsigned short)feat[eSrc[base+i]];
  }
}

// split-bf16 store of 8 values (16B per plane per lane)
__device__ __forceinline__ void store_split8(unsigned short* uh, unsigned short* ul,
                                             size_t node, int l16, const float* a){
  short8v hv, lv;
  #pragma unroll
  for (int i=0;i<8;i++){
    unsigned short hh = f2bf(a[i]);
    hv[i] = (short)hh;
    lv[i] = (short)f2bf(a[i] - bf2f(hh));
  }
  *(short8v*)&uh[node*C + l16*8] = hv;
  *(short8v*)&ul[node*C + l16*8] = lv;
}

// ---------- agg layer 1: quarter-wave per node; dinv via L2-hot table lookup ----------
// u[i] = split_bf16( dinv_i * ( dinv_i*embh[feat_i] + sum_e dinv[eSrc[e]]*embh[eFeat[e]] ) )

__global__ __launch_bounds__(256) void k_agg1(const __half* __restrict__ embh,
                      const unsigned short* __restrict__ eSrc, const unsigned short* __restrict__ eFeat,
                      const int* __restrict__ rowStart, const int* __restrict__ deg,
                      const float* __restrict__ dinv, const int* __restrict__ feat,
                      unsigned short* __restrict__ uh, unsigned short* __restrict__ ul){
  int t = threadIdx.x;
  int wave = t>>6, lane = t&63;
  int sub = lane>>4, l16 = lane&15;
  int node = blockIdx.x*16 + wave*4 + sub;
  if (node >= N_NODES) return;
  int rs = rowStart[node], len = deg[node];
  float dn = dinv[node];
  const short8v* E = (const short8v*)embh;   // 16 chunks per row
  float a[8];
  {
    short8v v = E[(size_t)feat[node]*16 + l16];
    #pragma unroll
    for (int i=0;i<8;i++) a[i] = dn * h2f(v[i]);
  }
  int k = 0;
  for (; k+8<=len; k+=8){
    int f[8]; float dd[8];
    #pragma unroll
    for (int j=0;j<8;j++){
      int e = rs+k+j;
      f[j] = eFeat[e];
      dd[j] = dinv[eSrc[e]];
    }
    short8v v[8];
    #pragma unroll
    for (int j=0;j<8;j++) v[j] = E[(size_t)f[j]*16 + l16];
    #pragma unroll
    for (int j=0;j<8;j++)
      #pragma unroll
      for (int i=0;i<8;i++) a[i] = fmaf(dd[j], h2f(v[j][i]), a[i]);
  }
  for (; k<len; k++){
    float dd = dinv[eSrc[rs+k]];
    short8v v = E[(size_t)eFeat[rs+k]*16 + l16];
    #pragma unroll
    for (int i=0;i<8;i++) a[i] = fmaf(dd, h2f(v[i]), a[i]);
  }
  #pragma unroll
  for (int i=0;i<8;i++) a[i] *= dn;
  store_split8(uh, ul, (size_t)node, l16, a);
}

// ---------- agg layers 2-3: quarter-wave per node ----------

__global__ __launch_bounds__(256) void k_aggS(const __half* __restrict__ xs, const unsigned short* __restrict__ eSrc,
                      const int* __restrict__ rowStart, const int* __restrict__ deg,
                      const float* __restrict__ dinv,
                      unsigned short* __restrict__ uh, unsigned short* __restrict__ ul){
  int t = threadIdx.x;
  int wave = t>>6, lane = t&63;
  int sub = lane>>4, l16 = lane&15;
  int node = blockIdx.x*16 + wave*4 + sub;
  if (node >= N_NODES) return;
  int rs = rowStart[node], len = deg[node];
  const short8v* X = (const short8v*)xs;   // 16 chunks per row
  float a[8];
  {
    short8v v = X[(size_t)node*16 + l16];
    #pragma unroll
    for (int i=0;i<8;i++) a[i] = h2f(v[i]);
  }
  int k = 0;
  for (; k+8<=len; k+=8){
    int s[8];
    #pragma unroll
    for (int j=0;j<8;j++) s[j] = eSrc[rs+k+j];
    short8v v[8];
    #pragma unroll
    for (int j=0;j<8;j++) v[j] = X[(size_t)s[j]*16 + l16];
    #pragma unroll
    for (int j=0;j<8;j++)
      #pragma unroll
      for (int i=0;i<8;i++) a[i] += h2f(v[j][i]);
  }
  for (; k<len; k++){
    short8v v = X[(size_t)eSrc[rs+k]*16 + l16];
    #pragma unroll
    for (int i=0;i<8;i++) a[i] += h2f(v[i]);
  }
  float dn = dinv[node];
  #pragma unroll
  for (int i=0;i<8;i++) a[i] *= dn;
  store_split8(uh, ul, (size_t)node, l16, a);
}

// ---------- gemm layers 1-2: xs = fp16( dinv * relu(u@W + b) ), zero-conversion MFMA ----------

__global__ __launch_bounds__(256) void k_gemmA(
            const unsigned short* __restrict__ uh, const unsigned short* __restrict__ ul,
            const short* __restrict__ Bh, const short* __restrict__ Bl,
            const float* __restrict__ bias, const float* __restrict__ dinv,
            __half* __restrict__ xs){
  int lane = threadIdx.x & 63;
  int pb = blockIdx.x*4 + (threadIdx.x >> 6);
  int R0 = pb*16;
  if (R0 >= N_NODES) return;
  int r15 = lane & 15, q = lane >> 4;
  int row = R0 + r15;
  const short8v* AH = (const short8v*)(uh + (size_t)row*C);
  const short8v* AL = (const short8v*)(ul + (size_t)row*C);
  const short8v* BH = (const short8v*)Bh;
  const short8v* BL = (const short8v*)Bl;
  f32x4 acc[8];
  #pragma unroll
  for (int ct=0;ct<8;ct++) acc[ct] = (f32x4){0.f,0.f,0.f,0.f};
  #pragma unroll
  for (int kt=0; kt<4; kt++){
    short8v ah = AH[kt*4 + q];
    short8v al = AL[kt*4 + q];
    #pragma unroll
    for (int ct=0; ct<8; ct++){
      short8v bh = BH[(kt*8+ct)*64 + lane];
      short8v bl = BL[(kt*8+ct)*64 + lane];
      acc[ct] = __builtin_amdgcn_mfma_f32_16x16x32_bf16(ah, bh, acc[ct], 0, 0, 0);
      acc[ct] = __builtin_amdgcn_mfma_f32_16x16x32_bf16(al, bh, acc[ct], 0, 0, 0);
      acc[ct] = __builtin_amdgcn_mfma_f32_16x16x32_bf16(ah, bl, acc[ct], 0, 0, 0);
    }
  }
  float bb[8];
  #pragma unroll
  for (int ct=0;ct<8;ct++) bb[ct] = bias[ct*16 + r15];
  #pragma unroll
  for (int j=0;j<4;j++){
    int rz = R0 + q*4 + j;
    float d = dinv[rz];
    #pragma unroll
    for (int ct=0; ct<8; ct++){
      float v = fmaxf(acc[ct][j] + bb[ct], 0.f);
      xs[(size_t)rz*C + ct*16 + r15] = __float2half(v * d);
    }
  }
}

// ---------- gemm layer 3: dots[i] = relu(u@W3 + b3) . fcW ----------

__global__ __launch_bounds__(256) void k_gemm3(
            const unsigned short* __restrict__ uh, const unsigned short* __restrict__ ul,
            const short* __restrict__ Bh, const short* __restrict__ Bl,
            const float* __restrict__ bias, const float* __restrict__ fcW,
            float* __restrict__ dots){
  int lane = threadIdx.x & 63;
  int pb = blockIdx.x*4 + (threadIdx.x >> 6);
  int R0 = pb*16;
  if (R0 >= N_NODES) return;
  int r15 = lane & 15, q = lane >> 4;
  int row = R0 + r15;
  const short8v* AH = (const short8v*)(uh + (size_t)row*C);
  const short8v* AL = (const short8v*)(ul + (size_t)row*C);
  const short8v* BH = (const short8v*)Bh;
  const short8v* BL = (const short8v*)Bl;
  f32x4 acc[8];
  #pragma unroll
  for (int ct=0;ct<8;ct++) acc[ct] = (f32x4){0.f,0.f,0.f,0.f};
  #pragma unroll
  for (int kt=0; kt<4; kt++){
    short8v ah = AH[kt*4 + q];
    short8v al = AL[kt*4 + q];
    #pragma unroll
    for (int ct=0; ct<8; ct++){
      short8v bh = BH[(kt*8+ct)*64 + lane];
      short8v bl = BL[(kt*8+ct)*64 + lane];
      acc[ct] = __builtin_amdgcn_mfma_f32_16x16x32_bf16(ah, bh, acc[ct], 0, 0, 0);
      acc[ct] = __builtin_amdgcn_mfma_f32_16x16x32_bf16(al, bh, acc[ct], 0, 0, 0);
      acc[ct] = __builtin_amdgcn_mfma_f32_16x16x32_bf16(ah, bl, acc[ct], 0, 0, 0);
    }
  }
  float bb[8], fw[8];
  #pragma unroll
  for (int ct=0;ct<8;ct++){ bb[ct] = bias[ct*16 + r15]; fw[ct] = fcW[ct*16 + r15]; }
  #pragma unroll
  for (int j=0;j<4;j++){
    int rz = R0 + q*4 + j;
    float s = 0.f;
    #pragma unroll
    for (int ct=0; ct<8; ct++)
      s += fmaxf(acc[ct][j] + bb[ct], 0.f) * fw[ct];
    s += __shfl_xor(s, 1);
    s += __shfl_xor(s, 2);
    s += __shfl_xor(s, 4);
    s += __shfl_xor(s, 8);
    if (r15 == 0) dots[rz] = s;
  }
}

// ---------- pooling ----------

__global__ void k_pool_seg(const float* __restrict__ dots, const int* __restrict__ gStart,
                           const float* __restrict__ fcb, float* __restrict__ out){
  __shared__ float s[256];
  int g = blockIdx.x;
  int st = gStart[g], en = gStart[g+1];
  float acc = 0.f;
  for (int i = st + threadIdx.x; i < en; i += 256) acc += dots[i];
  s[threadIdx.x] = acc; __syncthreads();
  for (int off=128; off>0; off>>=1){
    if (threadIdx.x < off) s[threadIdx.x] += s[threadIdx.x+off];
    __syncthreads();
  }
  if (threadIdx.x==0) out[g] = s[0]/fmaxf((float)(en-st),1.0f) + fcb[0];
}

// ---------- launch ----------

extern "C" void kernel_launch(void* const* d_in, const int* in_sizes, int n_in,
                              void* d_out, int out_size, void* d_ws, size_t ws_size,
                              hipStream_t stream){
  const int* edge  = (const int*)d_in[0];
  const int* srcI  = edge;
  const int* dstI  = edge + N_EDGES;
  const int* feat  = (const int*)d_in[1];
  const int* batch = (const int*)d_in[2];
  const float* emb = (const float*)d_in[3];
  const float* W1  = (const float*)d_in[4];
  const float* b1  = (const float*)d_in[5];
  const float* W2  = (const float*)d_in[6];
  const float* b2  = (const float*)d_in[7];
  const float* W3  = (const float*)d_in[8];
  const float* b3  = (const float*)d_in[9];
  const float* fcW = (const float*)d_in[10];
  const float* fcb = (const float*)d_in[11];
  float* out = (float*)d_out;

  __half* xs = (__half*)d_ws;                        // N*C f16 (gather target)
  unsigned short* uhp = (unsigned short*)(xs + (size_t)N_NODES*C);  // N*C u16
  unsigned short* ulp = uhp + (size_t)N_NODES*C;     // N*C u16
  __half* embh = (__half*)(ulp + (size_t)N_NODES*C); // VOCAB*C f16
  unsigned* binned = (unsigned*)(embh + (size_t)VOCAB*C); // 800000 u32
  unsigned short* eSrc  = (unsigned short*)(binned + N_EDGES);  // 800000 u16
  unsigned short* eFeat = eSrc + N_EDGES;            // 800000 u16
  int* rowStart = (int*)(eFeat + N_EDGES);           // 50000
  int* deg      = rowStart + N_NODES;                // 50000
  float* dinv   = (float*)(deg + N_NODES);           // 50000
  int* blockHist = (int*)(dinv + N_NODES);           // 256*200
  int* blockOfs  = blockHist + 256*A_BLOCKS;         // 256*200
  int* bucketTot = blockOfs + 256*A_BLOCKS;          // 256
  int* gStart    = bucketTot + 256;                  // 513 (+pad)
  float* dots   = (float*)(gStart + 520);            // 50000
  short* Bpack  = (short*)(dots + N_NODES);          // 6*16384 shorts
  short* Bh1 = Bpack,           * Bl1 = Bpack + 16384;
  short* Bh2 = Bpack + 2*16384, * Bl2 = Bpack + 3*16384;
  short* Bh3 = Bpack + 4*16384, * Bl3 = Bpack + 5*16384;

  k_pre       <<<A_BLOCKS+NBUCK+24+64, 256, 0, stream>>>(dstI, blockHist, batch, gStart,
                                                         W1, W2, W3, Bpack, emb, embh);
  k_binScanA  <<<256, 64, 0, stream>>>(blockHist, blockOfs, bucketTot);
  k_binScatter<<<A_BLOCKS, 256, 0, stream>>>(srcI, dstI, bucketTot, blockOfs, binned);
  k_binFinal  <<<NBUCK, 256, 0, stream>>>(binned, bucketTot, feat, eSrc, eFeat,
                                          rowStart, deg, dinv);

  int aggBlocks  = (N_NODES+15)/16;      // 3125 (16 nodes per block, 4 per wave)
  int gemmBlocks = (N_NODES/16 + 3)/4;   // 782 (1 row-tile per wave)
  // layer 1: aggregate in embedding space, then GEMM
  k_agg1 <<<aggBlocks, 256, 0, stream>>>(embh, eSrc, eFeat, rowStart, deg, dinv, feat, uhp, ulp);
  k_gemmA<<<gemmBlocks, 256, 0, stream>>>(uhp, ulp, Bh1, Bl1, b1, dinv, xs);
  // layer 2
  k_aggS <<<aggBlocks, 256, 0, stream>>>(xs, eSrc, rowStart, deg, dinv, uhp, ulp);
  k_gemmA<<<gemmBlocks, 256, 0, stream>>>(uhp, ulp, Bh2, Bl2, b2, dinv, xs);
  // layer 3: gemm emits per-node dot with fcW directly
  k_aggS <<<aggBlocks, 256, 0, stream>>>(xs, eSrc, rowStart, deg, dinv, uhp, ulp);
  k_gemm3<<<gemmBlocks, 256, 0, stream>>>(uhp, ulp, Bh3, Bl3, b3, fcW, dots);

  k_pool_seg<<<N_GRAPHS, 256, 0, stream>>>(dots, gStart, fcb, out);
}

// Round 13
// 168.293 us; speedup vs baseline: 1.6628x; 1.1491x over previous
//
#include <hip/hip_runtime.h>
#include <hip/hip_fp16.h>

#define N_NODES 50000
#define N_EDGES 800000
#define N_GRAPHS 512
#define VOCAB 10000
#define C 128
#define NBUCK 196            // ceil(50000/256), bucket = dst>>8
#define A_BLOCKS 200         // 4000 edges each
#define EDGES_PER_A (N_EDGES / A_BLOCKS)
#define SE_CAP 8192          // LDS eSrc staging per bucket (mean 4096)

typedef __attribute__((ext_vector_type(8))) short short8v;
typedef __attribute__((ext_vector_type(4))) float f32x4;

__device__ __forceinline__ unsigned short f2bf(float f){
  unsigned u = __builtin_bit_cast(unsigned, f);
  unsigned r = u + 0x7FFFu + ((u >> 16) & 1u);
  return (unsigned short)(r >> 16);
}
__device__ __forceinline__ float bf2f(unsigned short h){
  unsigned u = ((unsigned)h) << 16;
  return __builtin_bit_cast(float, u);
}
__device__ __forceinline__ float h2f(short s){
  return __half2float(__builtin_bit_cast(__half, (unsigned short)s));
}

// ---------- K1: binCount (200) | gstart (196) | W-prepack (24) | emb->fp16 (64) ----------
__global__ __launch_bounds__(256) void k_pre(const int* __restrict__ dst, int* __restrict__ blockHist,
                      const int* __restrict__ batch, int* __restrict__ gStart,
                      const float* __restrict__ W1, const float* __restrict__ W2,
                      const float* __restrict__ W3, short* __restrict__ Bp,
                      const float* __restrict__ emb, __half* __restrict__ embh){
  __shared__ int h[256];
  int b = blockIdx.x, t = threadIdx.x;
  if (b < A_BLOCKS){                    // binCount (bucket-major store)
    h[t] = 0; __syncthreads();
    int base = b * EDGES_PER_A;
    for (int i = t; i < EDGES_PER_A; i += 256)
      atomicAdd(&h[dst[base+i] >> 8], 1);
    __syncthreads();
    blockHist[t*A_BLOCKS + b] = h[t];
  } else if (b < A_BLOCKS+NBUCK){       // gstart
    int i = (b-A_BLOCKS)*256 + t;
    if (i >= N_NODES) return;
    int bb = batch[i];
    int pb = (i==0) ? -1 : batch[i-1];
    for (int g=pb+1; g<=bb; g++) gStart[g] = i;
    if (i == N_NODES-1)
      for (int g=bb+1; g<=N_GRAPHS; g++) gStart[g] = N_NODES;
  } else if (b < A_BLOCKS+NBUCK+24){    // W prepack (3 layers x 2048 threads)
    int idx = (b-A_BLOCKS-NBUCK)*256 + t;  // 0..6143
    int layer = idx / 2048;
    int r = idx - layer*2048;
    const float* W = (layer==0) ? W1 : (layer==1) ? W2 : W3;
    short* Bh = Bp + (size_t)layer*32768;
    short* Bl = Bh + 16384;
    int lane = r & 63, tile = r >> 6;   // tile = kt*8 + ct
    int kt = tile >> 3, ct = tile & 7;
    int q = lane >> 4, c = ct*16 + (lane & 15);
    #pragma unroll
    for (int i=0;i<8;i++){
      int k = kt*32 + q*8 + i;
      float w = W[k*C + c];
      unsigned short hh = f2bf(w);
      unsigned short ll = f2bf(w - bf2f(hh));
      Bh[(size_t)(tile*64 + lane)*8 + i] = (short)hh;
      Bl[(size_t)(tile*64 + lane)*8 + i] = (short)ll;
    }
  } else {                              // emb -> fp16 (64 blocks)
    int idx = (b-A_BLOCKS-NBUCK-24)*256 + t;
    const float2* s = (const float2*)emb;
    __half2* d2 = (__half2*)embh;
    for (int i = idx; i < VOCAB*C/2; i += 64*256)
      d2[i] = __float22half2_rn(s[i]);
  }
}

// ---------- scan A: wave per bucket, prefix over 200 block entries ----------
__global__ __launch_bounds__(64) void k_binScanA(const int* __restrict__ blockHist,
                        int* __restrict__ blockOfs, int* __restrict__ bucketTot){
  int b = blockIdx.x;        // bucket (0..255)
  int l = threadIdx.x;       // lane
  int carry = 0;
  for (int c = 0; c < 256; c += 64){
    int idx = c + l;
    int v = (idx < A_BLOCKS) ? blockHist[b*A_BLOCKS + idx] : 0;
    int x = v;
    #pragma unroll
    for (int off=1; off<64; off<<=1){
      int y = __shfl_up(x, off);
      if (l >= off) x += y;
    }
    if (idx < A_BLOCKS) blockOfs[b*A_BLOCKS + idx] = carry + x - v;  // exclusive
    carry += __shfl(x, 63);
  }
  if (l == 0) bucketTot[b] = carry;
}

// ---------- binning A2: scatter packed edges (bucket bases scanned in-block) ----------
__global__ __launch_bounds__(256) void k_binScatter(const int* __restrict__ src, const int* __restrict__ dst,
                           const int* __restrict__ bucketTot, const int* __restrict__ blockOfs,
                           unsigned* __restrict__ binned){
  __shared__ int s[256], ofs[256], cur[256];
  int t = threadIdx.x;
  int tv = bucketTot[t];
  s[t] = tv; __syncthreads();
  for (int off=1; off<256; off<<=1){
    int u = (t>=off) ? s[t-off] : 0;
    __syncthreads();
    s[t] += u;
    __syncthreads();
  }
  ofs[t] = (s[t] - tv) + blockOfs[t*A_BLOCKS + blockIdx.x];
  cur[t] = 0;
  __syncthreads();
  int base = blockIdx.x * EDGES_PER_A;
  for (int i = t; i < EDGES_PER_A; i += 256){
    int d = dst[base+i];
    int b = d >> 8;
    int p = atomicAdd(&cur[b], 1);
    binned[ofs[b] + p] = (unsigned)(src[base+i] & 0xFFFF) | ((unsigned)(d & 0xFF) << 16);
  }
}

// ---------- binning B: per-bucket CSR finalize + eFeat epilogue ----------
__global__ __launch_bounds__(256) void k_binFinal(const unsigned* __restrict__ binned,
                         const int* __restrict__ bucketTot, const int* __restrict__ feat,
                         unsigned short* __restrict__ eSrc, unsigned short* __restrict__ eFeat,
                         int* __restrict__ rowStart, int* __restrict__ deg, float* __restrict__ dinv){
  __shared__ int h[256], pre[256], cur[256], excl[256];
  __shared__ unsigned short sE[SE_CAP];
  int b = blockIdx.x;
  int t = threadIdx.x;
  int tv = bucketTot[t];
  pre[t] = tv; __syncthreads();
  for (int off=1; off<256; off<<=1){
    int u = (t>=off) ? pre[t-off] : 0;
    __syncthreads();
    pre[t] += u;
    __syncthreads();
  }
  excl[t] = pre[t] - tv;
  __syncthreads();
  int base = excl[b], cnt = bucketTot[b];
  int nodeBase = b << 8;
  h[t] = 0; __syncthreads();
  for (int i = t; i < cnt; i += 256)
    atomicAdd(&h[binned[base+i] >> 16], 1);
  __syncthreads();
  pre[t] = h[t]; __syncthreads();
  for (int off=1; off<256; off<<=1){
    int u = (t>=off) ? pre[t-off] : 0;
    __syncthreads();
    pre[t] += u;
    __syncthreads();
  }
  int node = nodeBase + t;
  if (node < N_NODES){
    int d = h[t];
    deg[node] = d;
    rowStart[node] = base + pre[t] - d;
    dinv[node] = rsqrtf((float)d + 1.0f);
  }
  cur[t] = pre[t] - h[t];
  __syncthreads();
  for (int i = t; i < cnt; i += 256){
    unsigned v = binned[base+i];
    int dl = v >> 16;
    int p = atomicAdd(&cur[dl], 1);
    unsigned short s = (unsigned short)(v & 0xFFFF);
    if (p < SE_CAP) sE[p] = s;
    else eSrc[base + p] = s;
  }
  __syncthreads();
  int lim = cnt < SE_CAP ? cnt : SE_CAP;
  for (int i = t; i < lim; i += 256){
    unsigned short sv = sE[i];
    eSrc[base+i]  = sv;
    eFeat[base+i] = (unsigned short)feat[sv];
  }
  for (int i = SE_CAP + t; i < cnt; i += 256){
    eFeat[base+i] = (unsigned short)feat[eSrc[base+i]];
  }
}

// ---------- fused layer: agg (quarter-wave/node, MLP=32/wave) -> LDS u-tile -> MFMA ----------
// block = 16 nodes = 1 GEMM row-tile. 50000 = 3125*16 exactly (no bounds code).
// LAYER 1: gather embh via eFeat, weight dinv[eSrc]; LAYER 2/3: gather xs via eSrc.
// LAYER 1/2 epilogue: xs = fp16(dinv*relu(acc+b)); LAYER 3: dots = relu(acc+b).fcW

template<int LAYER>
__global__ __launch_bounds__(256) void k_layer(
      const __half* __restrict__ gsrc,       // embh (L1) or xs (L2/3)
      const unsigned short* __restrict__ eSrc, const unsigned short* __restrict__ eFeat,
      const int* __restrict__ rowStart, const int* __restrict__ deg,
      const float* __restrict__ dinv, const int* __restrict__ feat,
      const short* __restrict__ Bh, const short* __restrict__ Bl,
      const float* __restrict__ bias, const float* __restrict__ fcW,
      __half* __restrict__ xsOut, float* __restrict__ dots){
  __shared__ unsigned short uhl[16*C];   // 4KB, XOR-swizzled
  __shared__ unsigned short ull[16*C];   // 4KB
  __shared__ float dotb[16][4];
  int t = threadIdx.x;
  int wave = t>>6, lane = t&63;
  int sub = lane>>4, l16 = lane&15;
  int node0 = blockIdx.x*16;
  int r = wave*4 + sub;                  // row in tile, 0..15
  int node = node0 + r;

  // ---- aggregation phase ----
  float a[8];
  {
    int rs = rowStart[node], len = deg[node];
    float dn = dinv[node];
    const short8v* X = (const short8v*)gsrc;
    if (LAYER == 1){
      short8v v = X[(size_t)feat[node]*16 + l16];
      #pragma unroll
      for (int i=0;i<8;i++) a[i] = dn * h2f(v[i]);
      int k = 0;
      for (; k+8<=len; k+=8){
        int f[8]; float dd[8];
        #pragma unroll
        for (int j=0;j<8;j++){
          int e = rs+k+j;
          f[j] = eFeat[e];
          dd[j] = dinv[eSrc[e]];
        }
        short8v v8[8];
        #pragma unroll
        for (int j=0;j<8;j++) v8[j] = X[(size_t)f[j]*16 + l16];
        #pragma unroll
        for (int j=0;j<8;j++)
          #pragma unroll
          for (int i=0;i<8;i++) a[i] = fmaf(dd[j], h2f(v8[j][i]), a[i]);
      }
      for (; k<len; k++){
        float dd = dinv[eSrc[rs+k]];
        short8v v1 = X[(size_t)eFeat[rs+k]*16 + l16];
        #pragma unroll
        for (int i=0;i<8;i++) a[i] = fmaf(dd, h2f(v1[i]), a[i]);
      }
    } else {
      short8v v = X[(size_t)node*16 + l16];
      #pragma unroll
      for (int i=0;i<8;i++) a[i] = h2f(v[i]);
      int k = 0;
      for (; k+8<=len; k+=8){
        int s[8];
        #pragma unroll
        for (int j=0;j<8;j++) s[j] = eSrc[rs+k+j];
        short8v v8[8];
        #pragma unroll
        for (int j=0;j<8;j++) v8[j] = X[(size_t)s[j]*16 + l16];
        #pragma unroll
        for (int j=0;j<8;j++)
          #pragma unroll
          for (int i=0;i<8;i++) a[i] += h2f(v8[j][i]);
      }
      for (; k<len; k++){
        short8v v1 = X[(size_t)eSrc[rs+k]*16 + l16];
        #pragma unroll
        for (int i=0;i<8;i++) a[i] += h2f(v1[i]);
      }
    }
    #pragma unroll
    for (int i=0;i<8;i++) a[i] *= dn;
  }
  // split-bf16 store to LDS (swizzle: 16B granularity, (r&7)<<4)
  {
    short8v hv, lv;
    #pragma unroll
    for (int i=0;i<8;i++){
      unsigned short hh = f2bf(a[i]);
      hv[i] = (short)hh;
      lv[i] = (short)f2bf(a[i] - bf2f(hh));
    }
    unsigned boff = (unsigned)(r*256 + l16*16) ^ ((unsigned)(r&7)<<4);
    *(short8v*)((char*)uhl + boff) = hv;
    *(short8v*)((char*)ull + boff) = lv;
  }
  __syncthreads();

  // ---- GEMM phase: wave owns column-tiles ct = 2*wave, 2*wave+1 ----
  int r15 = lane & 15, q = lane >> 4;
  const short8v* BH = (const short8v*)Bh;
  const short8v* BL = (const short8v*)Bl;
  f32x4 acc[2];
  acc[0] = (f32x4){0.f,0.f,0.f,0.f};
  acc[1] = (f32x4){0.f,0.f,0.f,0.f};
  #pragma unroll
  for (int kt=0; kt<4; kt++){
    unsigned boff = (unsigned)(r15*256 + (kt*4+q)*16) ^ ((unsigned)(r15&7)<<4);
    short8v ah = *(const short8v*)((const char*)uhl + boff);
    short8v al = *(const short8v*)((const char*)ull + boff);
    #pragma unroll
    for (int c=0;c<2;c++){
      int ct = wave*2 + c;
      short8v bh = BH[(kt*8+ct)*64 + lane];
      short8v bl = BL[(kt*8+ct)*64 + lane];
      acc[c] = __builtin_amdgcn_mfma_f32_16x16x32_bf16(ah, bh, acc[c], 0, 0, 0);
      acc[c] = __builtin_amdgcn_mfma_f32_16x16x32_bf16(al, bh, acc[c], 0, 0, 0);
      acc[c] = __builtin_amdgcn_mfma_f32_16x16x32_bf16(ah, bl, acc[c], 0, 0, 0);
    }
  }
  float bb[2] = { bias[(wave*2)*16 + r15], bias[(wave*2+1)*16 + r15] };
  if (LAYER == 3){
    float fw[2] = { fcW[(wave*2)*16 + r15], fcW[(wave*2+1)*16 + r15] };
    #pragma unroll
    for (int j=0;j<4;j++){
      float s = fmaxf(acc[0][j] + bb[0], 0.f)*fw[0]
              + fmaxf(acc[1][j] + bb[1], 0.f)*fw[1];
      s += __shfl_xor(s, 1);
      s += __shfl_xor(s, 2);
      s += __shfl_xor(s, 4);
      s += __shfl_xor(s, 8);
      if (r15 == 0) dotb[q*4 + j][wave] = s;
    }
    __syncthreads();
    if (t < 16) dots[node0 + t] = dotb[t][0] + dotb[t][1] + dotb[t][2] + dotb[t][3];
  } else {
    #pragma unroll
    for (int j=0;j<4;j++){
      int rz = node0 + q*4 + j;
      float d = dinv[rz];
      #pragma unroll
      for (int c=0;c<2;c++){
        float v = fmaxf(acc[c][j] + bb[c], 0.f);
        xsOut[(size_t)rz*C + (wave*2+c)*16 + r15] = __float2half(v * d);
      }
    }
  }
}

// ---------- pooling ----------

__global__ void k_pool_seg(const float* __restrict__ dots, const int* __restrict__ gStart,
                           const float* __restrict__ fcb, float* __restrict__ out){
  __shared__ float s[256];
  int g = blockIdx.x;
  int st = gStart[g], en = gStart[g+1];
  float acc = 0.f;
  for (int i = st + threadIdx.x; i < en; i += 256) acc += dots[i];
  s[threadIdx.x] = acc; __syncthreads();
  for (int off=128; off>0; off>>=1){
    if (threadIdx.x < off) s[threadIdx.x] += s[threadIdx.x+off];
    __syncthreads();
  }
  if (threadIdx.x==0) out[g] = s[0]/fmaxf((float)(en-st),1.0f) + fcb[0];
}

// ---------- launch ----------

extern "C" void kernel_launch(void* const* d_in, const int* in_sizes, int n_in,
                              void* d_out, int out_size, void* d_ws, size_t ws_size,
                              hipStream_t stream){
  const int* edge  = (const int*)d_in[0];
  const int* srcI  = edge;
  const int* dstI  = edge + N_EDGES;
  const int* feat  = (const int*)d_in[1];
  const int* batch = (const int*)d_in[2];
  const float* emb = (const float*)d_in[3];
  const float* W1  = (const float*)d_in[4];
  const float* b1  = (const float*)d_in[5];
  const float* W2  = (const float*)d_in[6];
  const float* b2  = (const float*)d_in[7];
  const float* W3  = (const float*)d_in[8];
  const float* b3  = (const float*)d_in[9];
  const float* fcW = (const float*)d_in[10];
  const float* fcb = (const float*)d_in[11];
  float* out = (float*)d_out;

  __half* xsA = (__half*)d_ws;                       // N*C f16
  __half* xsB = xsA + (size_t)N_NODES*C;             // N*C f16
  __half* embh = xsB + (size_t)N_NODES*C;            // VOCAB*C f16
  unsigned* binned = (unsigned*)(embh + (size_t)VOCAB*C); // 800000 u32
  unsigned short* eSrc  = (unsigned short*)(binned + N_EDGES);  // 800000 u16
  unsigned short* eFeat = eSrc + N_EDGES;            // 800000 u16
  int* rowStart = (int*)(eFeat + N_EDGES);           // 50000
  int* deg      = rowStart + N_NODES;                // 50000
  float* dinv   = (float*)(deg + N_NODES);           // 50000
  int* blockHist = (int*)(dinv + N_NODES);           // 256*200
  int* blockOfs  = blockHist + 256*A_BLOCKS;         // 256*200
  int* bucketTot = blockOfs + 256*A_BLOCKS;          // 256
  int* gStart    = bucketTot + 256;                  // 513 (+pad)
  float* dots   = (float*)(gStart + 520);            // 50000
  short* Bpack  = (short*)(dots + N_NODES);          // 6*16384 shorts
  short* Bh1 = Bpack,           * Bl1 = Bpack + 16384;
  short* Bh2 = Bpack + 2*16384, * Bl2 = Bpack + 3*16384;
  short* Bh3 = Bpack + 4*16384, * Bl3 = Bpack + 5*16384;

  k_pre       <<<A_BLOCKS+NBUCK+24+64, 256, 0, stream>>>(dstI, blockHist, batch, gStart,
                                                         W1, W2, W3, Bpack, emb, embh);
  k_binScanA  <<<256, 64, 0, stream>>>(blockHist, blockOfs, bucketTot);
  k_binScatter<<<A_BLOCKS, 256, 0, stream>>>(srcI, dstI, bucketTot, blockOfs, binned);
  k_binFinal  <<<NBUCK, 256, 0, stream>>>(binned, bucketTot, feat, eSrc, eFeat,
                                          rowStart, deg, dinv);

  int LBLOCKS = N_NODES/16;   // 3125 exactly
  k_layer<1><<<LBLOCKS, 256, 0, stream>>>(embh, eSrc, eFeat, rowStart, deg, dinv, feat,
                                          Bh1, Bl1, b1, nullptr, xsB, nullptr);
  k_layer<2><<<LBLOCKS, 256, 0, stream>>>(xsB, eSrc, nullptr, rowStart, deg, dinv, nullptr,
                                          Bh2, Bl2, b2, nullptr, xsA, nullptr);
  k_layer<3><<<LBLOCKS, 256, 0, stream>>>(xsA, eSrc, nullptr, rowStart, deg, dinv, nullptr,
                                          Bh3, Bl3, b3, fcW, nullptr, dots);

  k_pool_seg<<<N_GRAPHS, 256, 0, stream>>>(dots, gStart, fcb, out);
}

// Round 14
// 167.556 us; speedup vs baseline: 1.6701x; 1.0044x over previous
//
#include <hip/hip_runtime.h>
#include <hip/hip_fp16.h>

#define N_NODES 50000
#define N_EDGES 800000
#define N_GRAPHS 512
#define VOCAB 10000
#define C 128
#define NBUCK 196            // ceil(50000/256), bucket = dst>>8
#define A_BLOCKS 200         // 4000 edges each
#define EDGES_PER_A (N_EDGES / A_BLOCKS)
#define SE_CAP 8192          // LDS eSrc staging per bucket (mean 4096)

typedef __attribute__((ext_vector_type(8))) short short8v;
typedef __attribute__((ext_vector_type(4))) float f32x4;

__device__ __forceinline__ unsigned short f2bf(float f){
  unsigned u = __builtin_bit_cast(unsigned, f);
  unsigned r = u + 0x7FFFu + ((u >> 16) & 1u);
  return (unsigned short)(r >> 16);
}
__device__ __forceinline__ float bf2f(unsigned short h){
  unsigned u = ((unsigned)h) << 16;
  return __builtin_bit_cast(float, u);
}
__device__ __forceinline__ float h2f(short s){
  return __half2float(__builtin_bit_cast(__half, (unsigned short)s));
}

// ---------- K1: binCount (200) | gstart (196) | W-prepack (24) | emb->fp16 (64) ----------
__global__ __launch_bounds__(256) void k_pre(const int* __restrict__ dst, int* __restrict__ blockHist,
                      const int* __restrict__ batch, int* __restrict__ gStart,
                      const float* __restrict__ W1, const float* __restrict__ W2,
                      const float* __restrict__ W3, short* __restrict__ Bp,
                      const float* __restrict__ emb, __half* __restrict__ embh){
  __shared__ int h[256];
  int b = blockIdx.x, t = threadIdx.x;
  if (b < A_BLOCKS){                    // binCount (bucket-major store)
    h[t] = 0; __syncthreads();
    int base = b * EDGES_PER_A;
    for (int i = t; i < EDGES_PER_A; i += 256)
      atomicAdd(&h[dst[base+i] >> 8], 1);
    __syncthreads();
    blockHist[t*A_BLOCKS + b] = h[t];
  } else if (b < A_BLOCKS+NBUCK){       // gstart
    int i = (b-A_BLOCKS)*256 + t;
    if (i >= N_NODES) return;
    int bb = batch[i];
    int pb = (i==0) ? -1 : batch[i-1];
    for (int g=pb+1; g<=bb; g++) gStart[g] = i;
    if (i == N_NODES-1)
      for (int g=bb+1; g<=N_GRAPHS; g++) gStart[g] = N_NODES;
  } else if (b < A_BLOCKS+NBUCK+24){    // W prepack (3 layers x 2048 threads)
    int idx = (b-A_BLOCKS-NBUCK)*256 + t;  // 0..6143
    int layer = idx / 2048;
    int r = idx - layer*2048;
    const float* W = (layer==0) ? W1 : (layer==1) ? W2 : W3;
    short* Bh = Bp + (size_t)layer*32768;
    short* Bl = Bh + 16384;
    int lane = r & 63, tile = r >> 6;   // tile = kt*8 + ct
    int kt = tile >> 3, ct = tile & 7;
    int q = lane >> 4, c = ct*16 + (lane & 15);
    #pragma unroll
    for (int i=0;i<8;i++){
      int k = kt*32 + q*8 + i;
      float w = W[k*C + c];
      unsigned short hh = f2bf(w);
      unsigned short ll = f2bf(w - bf2f(hh));
      Bh[(size_t)(tile*64 + lane)*8 + i] = (short)hh;
      Bl[(size_t)(tile*64 + lane)*8 + i] = (short)ll;
    }
  } else {                              // emb -> fp16 (64 blocks)
    int idx = (b-A_BLOCKS-NBUCK-24)*256 + t;
    const float2* s = (const float2*)emb;
    __half2* d2 = (__half2*)embh;
    for (int i = idx; i < VOCAB*C/2; i += 64*256)
      d2[i] = __float22half2_rn(s[i]);
  }
}

// ---------- scan A: wave per bucket, prefix over 200 block entries ----------
__global__ __launch_bounds__(64) void k_binScanA(const int* __restrict__ blockHist,
                        int* __restrict__ blockOfs, int* __restrict__ bucketTot){
  int b = blockIdx.x;
  int l = threadIdx.x;
  int carry = 0;
  for (int c = 0; c < 256; c += 64){
    int idx = c + l;
    int v = (idx < A_BLOCKS) ? blockHist[b*A_BLOCKS + idx] : 0;
    int x = v;
    #pragma unroll
    for (int off=1; off<64; off<<=1){
      int y = __shfl_up(x, off);
      if (l >= off) x += y;
    }
    if (idx < A_BLOCKS) blockOfs[b*A_BLOCKS + idx] = carry + x - v;
    carry += __shfl(x, 63);
  }
  if (l == 0) bucketTot[b] = carry;
}

// ---------- binning A2: scatter packed edges (bucket bases scanned in-block) ----------
__global__ __launch_bounds__(256) void k_binScatter(const int* __restrict__ src, const int* __restrict__ dst,
                           const int* __restrict__ bucketTot, const int* __restrict__ blockOfs,
                           unsigned* __restrict__ binned){
  __shared__ int s[256], ofs[256], cur[256];
  int t = threadIdx.x;
  int tv = bucketTot[t];
  s[t] = tv; __syncthreads();
  for (int off=1; off<256; off<<=1){
    int u = (t>=off) ? s[t-off] : 0;
    __syncthreads();
    s[t] += u;
    __syncthreads();
  }
  ofs[t] = (s[t] - tv) + blockOfs[t*A_BLOCKS + blockIdx.x];
  cur[t] = 0;
  __syncthreads();
  int base = blockIdx.x * EDGES_PER_A;
  for (int i = t; i < EDGES_PER_A; i += 256){
    int d = dst[base+i];
    int b = d >> 8;
    int p = atomicAdd(&cur[b], 1);
    binned[ofs[b] + p] = (unsigned)(src[base+i] & 0xFFFF) | ((unsigned)(d & 0xFF) << 16);
  }
}

// ---------- binning B: CSR finalize + xs0 epilogue (xs0[n] = fp16(dinv_n * emb[feat_n])) ----------
__global__ __launch_bounds__(256) void k_binFinal(const unsigned* __restrict__ binned,
                         const int* __restrict__ bucketTot, const int* __restrict__ feat,
                         const __half* __restrict__ embh,
                         unsigned short* __restrict__ eSrc, __half* __restrict__ xs0,
                         int* __restrict__ rowStart, int* __restrict__ deg, float* __restrict__ dinv){
  __shared__ int h[256], pre[256], cur[256], excl[256];
  __shared__ float dinvS[256];
  __shared__ unsigned short sE[SE_CAP];
  int b = blockIdx.x;
  int t = threadIdx.x;
  int tv = bucketTot[t];
  pre[t] = tv; __syncthreads();
  for (int off=1; off<256; off<<=1){
    int u = (t>=off) ? pre[t-off] : 0;
    __syncthreads();
    pre[t] += u;
    __syncthreads();
  }
  excl[t] = pre[t] - tv;
  __syncthreads();
  int base = excl[b], cnt = bucketTot[b];
  int nodeBase = b << 8;
  h[t] = 0; __syncthreads();
  for (int i = t; i < cnt; i += 256)
    atomicAdd(&h[binned[base+i] >> 16], 1);
  __syncthreads();
  pre[t] = h[t]; __syncthreads();
  for (int off=1; off<256; off<<=1){
    int u = (t>=off) ? pre[t-off] : 0;
    __syncthreads();
    pre[t] += u;
    __syncthreads();
  }
  int node = nodeBase + t;
  float dn = 0.f;
  if (node < N_NODES){
    int d = h[t];
    deg[node] = d;
    rowStart[node] = base + pre[t] - d;
    dn = rsqrtf((float)d + 1.0f);
    dinv[node] = dn;
  }
  dinvS[t] = dn;
  cur[t] = pre[t] - h[t];
  __syncthreads();
  for (int i = t; i < cnt; i += 256){
    unsigned v = binned[base+i];
    int dl = v >> 16;
    int p = atomicAdd(&cur[dl], 1);
    unsigned short s = (unsigned short)(v & 0xFFFF);
    if (p < SE_CAP) sE[p] = s;
    else eSrc[base + p] = s;
  }
  __syncthreads();
  int lim = cnt < SE_CAP ? cnt : SE_CAP;
  for (int i = t; i < lim; i += 256) eSrc[base+i] = sE[i];
  // xs0 epilogue: 16 threads per node, 16 nodes per pass
  int l16 = t & 15;
  for (int n = t >> 4; n < 256; n += 16){
    int nd = nodeBase + n;
    if (nd < N_NODES){
      short8v v = ((const short8v*)embh)[(size_t)feat[nd]*16 + l16];
      float d = dinvS[n];
      short8v o;
      #pragma unroll
      for (int i=0;i<8;i++)
        o[i] = (short)__builtin_bit_cast(unsigned short, __float2half(d * h2f(v[i])));
      ((short8v*)xs0)[(size_t)nd*16 + l16] = o;
    }
  }
}

// ---------- fused layer: pipelined gather -> LDS u-tile -> MFMA ----------
// block = 16 nodes = 1 row-tile; quarter-wave per node; gather 3-stage pipelined:
// ids 2 batches ahead, rows 1 batch ahead, consume overlapped (8 rows in flight).
// u = dinv_node * (gsrc[node] + sum gsrc[eSrc]); LAYER<3: xs=fp16(dinv*relu(u@W+b)); 3: dots.

template<int LAYER>
__global__ __launch_bounds__(256, 4) void k_layer(
      const __half* __restrict__ gsrc,
      const unsigned short* __restrict__ eSrc,
      const int* __restrict__ rowStart, const int* __restrict__ deg,
      const float* __restrict__ dinv,
      const short* __restrict__ Bh, const short* __restrict__ Bl,
      const float* __restrict__ bias, const float* __restrict__ fcW,
      __half* __restrict__ xsOut, float* __restrict__ dots){
  __shared__ unsigned short uhl[16*C];
  __shared__ unsigned short ull[16*C];
  __shared__ float dotb[16][4];
  int t = threadIdx.x;
  int wave = t>>6, lane = t&63;
  int sub = lane>>4, l16 = lane&15;
  int node0 = blockIdx.x*16;
  int r = wave*4 + sub;
  int node = node0 + r;

  float a[8];
  {
    int rs = rowStart[node], len = deg[node];
    float dn = dinv[node];
    const short8v* X = (const short8v*)gsrc;
    short8v sv = X[(size_t)node*16 + l16];
    #pragma unroll
    for (int i=0;i<8;i++) a[i] = h2f(sv[i]);

    int nb = len >> 3;
    int k = nb << 3;
    if (nb >= 2){
      int iA[8], iB[8];
      short8v rA[8], rB[8];
      #pragma unroll
      for (int j=0;j<8;j++) iA[j] = eSrc[rs+j];
      #pragma unroll
      for (int j=0;j<8;j++) iB[j] = eSrc[rs+8+j];
      #pragma unroll
      for (int j=0;j<8;j++) rA[j] = X[(size_t)iA[j]*16 + l16];
      for (int c=2; c<nb; c++){
        int iC[8];
        #pragma unroll
        for (int j=0;j<8;j++) iC[j] = eSrc[rs + c*8 + j];
        #pragma unroll
        for (int j=0;j<8;j++) rB[j] = X[(size_t)iB[j]*16 + l16];
        #pragma unroll
        for (int j=0;j<8;j++)
          #pragma unroll
          for (int i=0;i<8;i++) a[i] += h2f(rA[j][i]);
        #pragma unroll
        for (int j=0;j<8;j++){ rA[j]=rB[j]; iB[j]=iC[j]; }
      }
      #pragma unroll
      for (int j=0;j<8;j++) rB[j] = X[(size_t)iB[j]*16 + l16];
      #pragma unroll
      for (int j=0;j<8;j++)
        #pragma unroll
        for (int i=0;i<8;i++) a[i] += h2f(rA[j][i]);
      #pragma unroll
      for (int j=0;j<8;j++)
        #pragma unroll
        for (int i=0;i<8;i++) a[i] += h2f(rB[j][i]);
    } else if (nb == 1){
      int s1[8]; short8v v1[8];
      #pragma unroll
      for (int j=0;j<8;j++) s1[j] = eSrc[rs+j];
      #pragma unroll
      for (int j=0;j<8;j++) v1[j] = X[(size_t)s1[j]*16 + l16];
      #pragma unroll
      for (int j=0;j<8;j++)
        #pragma unroll
        for (int i=0;i<8;i++) a[i] += h2f(v1[j][i]);
    }
    int rem = len - k;
    if (rem > 0){
      int sR[7]; short8v vR[7];
      #pragma unroll
      for (int j=0;j<7;j++) sR[j] = (j < rem) ? (int)eSrc[rs+k+j] : node;
      #pragma unroll
      for (int j=0;j<7;j++) vR[j] = X[(size_t)sR[j]*16 + l16];
      #pragma unroll
      for (int j=0;j<7;j++){
        if (j < rem){
          #pragma unroll
          for (int i=0;i<8;i++) a[i] += h2f(vR[j][i]);
        }
      }
    }
    #pragma unroll
    for (int i=0;i<8;i++) a[i] *= dn;
  }
  // split-bf16 store to LDS (16B-granularity XOR swizzle)
  {
    short8v hv, lv;
    #pragma unroll
    for (int i=0;i<8;i++){
      unsigned short hh = f2bf(a[i]);
      hv[i] = (short)hh;
      lv[i] = (short)f2bf(a[i] - bf2f(hh));
    }
    unsigned boff = (unsigned)(r*256 + l16*16) ^ ((unsigned)(r&7)<<4);
    *(short8v*)((char*)uhl + boff) = hv;
    *(short8v*)((char*)ull + boff) = lv;
  }
  __syncthreads();

  // ---- GEMM phase: wave owns column-tiles ct = 2*wave, 2*wave+1 ----
  int r15 = lane & 15, q = lane >> 4;
  const short8v* BH = (const short8v*)Bh;
  const short8v* BL = (const short8v*)Bl;
  f32x4 acc[2];
  acc[0] = (f32x4){0.f,0.f,0.f,0.f};
  acc[1] = (f32x4){0.f,0.f,0.f,0.f};
  #pragma unroll
  for (int kt=0; kt<4; kt++){
    unsigned boff = (unsigned)(r15*256 + (kt*4+q)*16) ^ ((unsigned)(r15&7)<<4);
    short8v ah = *(const short8v*)((const char*)uhl + boff);
    short8v al = *(const short8v*)((const char*)ull + boff);
    #pragma unroll
    for (int c=0;c<2;c++){
      int ct = wave*2 + c;
      short8v bh = BH[(kt*8+ct)*64 + lane];
      short8v bl = BL[(kt*8+ct)*64 + lane];
      acc[c] = __builtin_amdgcn_mfma_f32_16x16x32_bf16(ah, bh, acc[c], 0, 0, 0);
      acc[c] = __builtin_amdgcn_mfma_f32_16x16x32_bf16(al, bh, acc[c], 0, 0, 0);
      acc[c] = __builtin_amdgcn_mfma_f32_16x16x32_bf16(ah, bl, acc[c], 0, 0, 0);
    }
  }
  float bb[2] = { bias[(wave*2)*16 + r15], bias[(wave*2+1)*16 + r15] };
  if (LAYER == 3){
    float fw[2] = { fcW[(wave*2)*16 + r15], fcW[(wave*2+1)*16 + r15] };
    #pragma unroll
    for (int j=0;j<4;j++){
      float s = fmaxf(acc[0][j] + bb[0], 0.f)*fw[0]
              + fmaxf(acc[1][j] + bb[1], 0.f)*fw[1];
      s += __shfl_xor(s, 1);
      s += __shfl_xor(s, 2);
      s += __shfl_xor(s, 4);
      s += __shfl_xor(s, 8);
      if (r15 == 0) dotb[q*4 + j][wave] = s;
    }
    __syncthreads();
    if (t < 16) dots[node0 + t] = dotb[t][0] + dotb[t][1] + dotb[t][2] + dotb[t][3];
  } else {
    #pragma unroll
    for (int j=0;j<4;j++){
      int rz = node0 + q*4 + j;
      float d = dinv[rz];
      #pragma unroll
      for (int c=0;c<2;c++){
        float v = fmaxf(acc[c][j] + bb[c], 0.f);
        xsOut[(size_t)rz*C + (wave*2+c)*16 + r15] = __float2half(v * d);
      }
    }
  }
}

// ---------- pooling ----------

__global__ void k_pool_seg(const float* __restrict__ dots, const int* __restrict__ gStart,
                           const float* __restrict__ fcb, float* __restrict__ out){
  __shared__ float s[256];
  int g = blockIdx.x;
  int st = gStart[g], en = gStart[g+1];
  float acc = 0.f;
  for (int i = st + threadIdx.x; i < en; i += 256) acc += dots[i];
  s[threadIdx.x] = acc; __syncthreads();
  for (int off=128; off>0; off>>=1){
    if (threadIdx.x < off) s[threadIdx.x] += s[threadIdx.x+off];
    __syncthreads();
  }
  if (threadIdx.x==0) out[g] = s[0]/fmaxf((float)(en-st),1.0f) + fcb[0];
}

// ---------- launch ----------

extern "C" void kernel_launch(void* const* d_in, const int* in_sizes, int n_in,
                              void* d_out, int out_size, void* d_ws, size_t ws_size,
                              hipStream_t stream){
  const int* edge  = (const int*)d_in[0];
  const int* srcI  = edge;
  const int* dstI  = edge + N_EDGES;
  const int* feat  = (const int*)d_in[1];
  const int* batch = (const int*)d_in[2];
  const float* emb = (const float*)d_in[3];
  const float* W1  = (const float*)d_in[4];
  const float* b1  = (const float*)d_in[5];
  const float* W2  = (const float*)d_in[6];
  const float* b2  = (const float*)d_in[7];
  const float* W3  = (const float*)d_in[8];
  const float* b3  = (const float*)d_in[9];
  const float* fcW = (const float*)d_in[10];
  const float* fcb = (const float*)d_in[11];
  float* out = (float*)d_out;

  __half* xsA = (__half*)d_ws;                       // N*C f16
  __half* xsB = xsA + (size_t)N_NODES*C;             // N*C f16
  __half* xs0 = xsB + (size_t)N_NODES*C;             // N*C f16
  __half* embh = xs0 + (size_t)N_NODES*C;            // VOCAB*C f16
  unsigned* binned = (unsigned*)(embh + (size_t)VOCAB*C); // 800000 u32
  unsigned short* eSrc  = (unsigned short*)(binned + N_EDGES);  // 800000 u16
  int* rowStart = (int*)(eSrc + N_EDGES);            // 50000
  int* deg      = rowStart + N_NODES;                // 50000
  float* dinv   = (float*)(deg + N_NODES);           // 50000
  int* blockHist = (int*)(dinv + N_NODES);           // 256*200
  int* blockOfs  = blockHist + 256*A_BLOCKS;         // 256*200
  int* bucketTot = blockOfs + 256*A_BLOCKS;          // 256
  int* gStart    = bucketTot + 256;                  // 513 (+pad)
  float* dots   = (float*)(gStart + 520);            // 50000
  short* Bpack  = (short*)(dots + N_NODES);          // 6*16384 shorts
  short* Bh1 = Bpack,           * Bl1 = Bpack + 16384;
  short* Bh2 = Bpack + 2*16384, * Bl2 = Bpack + 3*16384;
  short* Bh3 = Bpack + 4*16384, * Bl3 = Bpack + 5*16384;

  k_pre       <<<A_BLOCKS+NBUCK+24+64, 256, 0, stream>>>(dstI, blockHist, batch, gStart,
                                                         W1, W2, W3, Bpack, emb, embh);
  k_binScanA  <<<256, 64, 0, stream>>>(blockHist, blockOfs, bucketTot);
  k_binScatter<<<A_BLOCKS, 256, 0, stream>>>(srcI, dstI, bucketTot, blockOfs, binned);
  k_binFinal  <<<NBUCK, 256, 0, stream>>>(binned, bucketTot, feat, embh, eSrc, xs0,
                                          rowStart, deg, dinv);

  int LBLOCKS = N_NODES/16;   // 3125 exactly
  k_layer<1><<<LBLOCKS, 256, 0, stream>>>(xs0, eSrc, rowStart, deg, dinv,
                                          Bh1, Bl1, b1, nullptr, xsB, nullptr);
  k_layer<2><<<LBLOCKS, 256, 0, stream>>>(xsB, eSrc, rowStart, deg, dinv,
                                          Bh2, Bl2, b2, nullptr, xsA, nullptr);
  k_layer<3><<<LBLOCKS, 256, 0, stream>>>(xsA, eSrc, rowStart, deg, dinv,
                                          Bh3, Bl3, b3, fcW, nullptr, dots);

  k_pool_seg<<<N_GRAPHS, 256, 0, stream>>>(dots, gStart, fcb, out);
}